// Round 16
// baseline (666.487 us; speedup 1.0000x reference)
//
#include <hip/hip_runtime.h>

#define N_PIX 1024      // 32*32 pixels per image
#define BATCH 32
#define CCH 256         // channels == code dim
#define KCODES 4096
#define NROWS 32768     // BATCH * N_PIX
#define DELTA 0.0625f   // rescore margin (approx-score error bound ~0.003 typ, 0.05 worst)

typedef __attribute__((ext_vector_type(8))) short bf16x8;
typedef __attribute__((ext_vector_type(4))) float f32x4;

// ---- ws layout (bytes) ----
#define OFF_ESQ   0u
#define OFF_BIDX  16384u
#define OFF_FLAGS 147456u
#define OFF_PART  278528u
#define OFF_TOP2  524288u                    // 64 chunks x 32768 rows x float4 = 32 MB
#define OFF_A     34078720u                  // 256 mtiles(128r) x 16 sub x 8 KB = 32 MB (subtile, pre-swizzled)
#define OFF_B     67633152u                  // 32 ntiles(128r) x 16 sub x 8 KB = 4 MB (subtile, pre-swizzled)
#define WS_NEEDED 71827456u
// list/res/cnt live INSIDE the A region (dead after mfma_top2; rewritten every call by conv_x first)
#define OFF_LIST  OFF_A                      // 32768 i32 = 128 KB
#define OFF_RES   (OFF_A + 131072u)          // 32768 u64 = 256 KB
#define OFF_CNT   (OFF_A + 131072u + 262144u)

// swizzle for 64-B rows: spreads 16-lane b128 quarters over all 8 bank-groups
// per 8 rows. Applied at conv (pre-swizzled global) + ds_read (same involution).
#define ROWSWZ(row) ((((row) >> 1) & 3) << 4)

// round-to-nearest-even fp32 -> bf16 bits
__device__ __forceinline__ unsigned short f2bf(float v) {
    unsigned u = __float_as_uint(v);
    return (unsigned short)((u + 0x7FFFu + ((u >> 16) & 1u)) >> 16);
}
__device__ __forceinline__ float bf2f(unsigned short h) {
    return __uint_as_float(((unsigned)h) << 16);
}
// monotone float -> uint (total order preserving)
__device__ __forceinline__ unsigned mono(float s) {
    unsigned u = __float_as_uint(s);
    return (u & 0x80000000u) ? ~u : (u | 0x80000000u);
}

__device__ __forceinline__ void gload_lds16(const void* g, void* l) {
    __builtin_amdgcn_global_load_lds(
        (const __attribute__((address_space(1))) unsigned int*)g,
        (__attribute__((address_space(3))) unsigned int*)l, 16, 0, 0);
}

// ---------------- kernel 0: e_sq[k] = sum_c emb[k][c]^2 (exact fp32) ----------------
__global__ __launch_bounds__(256) void esq_kernel(const float* __restrict__ emb,
                                                  float* __restrict__ esq) {
    const int t = threadIdx.x;
    const int w = t >> 6, l = t & 63;
    const int k = blockIdx.x * 4 + w;
    const float4 v = *(const float4*)(emb + (size_t)k * CCH + l * 4);
    float s = v.x * v.x + v.y * v.y + v.z * v.z + v.w * v.w;
#pragma unroll
    for (int off = 32; off > 0; off >>= 1) s += __shfl_down(s, off);
    if (l == 0) esq[k] = s;
}

// ---------------- conv_x: x fp32 NCHW -> interleaved pre-swizzled bf16 hi/lo subtiles ----------------
// A[mtile128][sub 16][128 rows x 64 B]; sub = kt*2+half (hi), +8 (lo). 128 KB/mtile.
__global__ __launch_bounds__(256) void conv_x_kernel(const float* __restrict__ x,
                                                     char* __restrict__ A) {
    const int t = threadIdx.x;
    const int m = blockIdx.x * 64 + (t & 63);
    const int kt = t >> 6;                       // 0..3
    const int b = m >> 10, p = m & 1023;
    const float* src = x + ((size_t)b * CCH + kt * 64) * N_PIX + p;
    const int row = m & 127;
    char* tbase = A + (size_t)(m >> 7) * 131072;   // 128 KB per mtile
    const int swz = ROWSWZ(row);
#pragma unroll
    for (int g = 0; g < 8; ++g) {
        unsigned hv[4], lv[4];
#pragma unroll
        for (int e2 = 0; e2 < 4; ++e2) {
            const float v0 = src[(size_t)(g * 8 + e2 * 2 + 0) * N_PIX];
            const float v1 = src[(size_t)(g * 8 + e2 * 2 + 1) * N_PIX];
            const unsigned short h0 = f2bf(v0), h1 = f2bf(v1);
            const unsigned short l0 = f2bf(v0 - bf2f(h0)), l1 = f2bf(v1 - bf2f(h1));
            hv[e2] = (unsigned)h0 | ((unsigned)h1 << 16);
            lv[e2] = (unsigned)l0 | ((unsigned)l1 << 16);
        }
        const int sub_hi = kt * 2 + (g >> 2);            // 0..7
        const int byte = (row * 64 + (g & 3) * 16) ^ swz;
        *(uint4*)(tbase + sub_hi * 8192 + byte)       = make_uint4(hv[0], hv[1], hv[2], hv[3]);
        *(uint4*)(tbase + (8 + sub_hi) * 8192 + byte) = make_uint4(lv[0], lv[1], lv[2], lv[3]);
    }
}

// ---------------- conv_e: embedding fp32 -> interleaved pre-swizzled bf16 hi/lo subtiles ----------------
__global__ __launch_bounds__(256) void conv_e_kernel(const float* __restrict__ emb,
                                                     char* __restrict__ B,
                                                     int* __restrict__ cnt) {
    const int t = threadIdx.x;
    if (blockIdx.x == 0 && t == 0) *cnt = 0;   // runs after conv_x (which clobbers this region)
    const int n = blockIdx.x * 64 + (t & 63);
    const int kt = t >> 6;
    const float* src = emb + (size_t)n * CCH + kt * 64;
    const int row = n & 127;
    char* tbase = B + (size_t)(n >> 7) * 131072;   // 128 KB per ntile
    const int swz = ROWSWZ(row);
#pragma unroll
    for (int g = 0; g < 8; ++g) {
        const float4 a = *(const float4*)(src + g * 8);
        const float4 c = *(const float4*)(src + g * 8 + 4);
        const float vr[8] = {a.x, a.y, a.z, a.w, c.x, c.y, c.z, c.w};
        unsigned hv[4], lv[4];
#pragma unroll
        for (int e2 = 0; e2 < 4; ++e2) {
            const unsigned short h0 = f2bf(vr[e2 * 2]), h1 = f2bf(vr[e2 * 2 + 1]);
            const unsigned short l0 = f2bf(vr[e2 * 2] - bf2f(h0));
            const unsigned short l1 = f2bf(vr[e2 * 2 + 1] - bf2f(h1));
            hv[e2] = (unsigned)h0 | ((unsigned)h1 << 16);
            lv[e2] = (unsigned)l0 | ((unsigned)l1 << 16);
        }
        const int sub_hi = kt * 2 + (g >> 2);
        const int byte = (row * 64 + (g & 3) * 16) ^ swz;
        *(uint4*)(tbase + sub_hi * 8192 + byte)       = make_uint4(hv[0], hv[1], hv[2], hv[3]);
        *(uint4*)(tbase + (8 + sub_hi) * 8192 + byte) = make_uint4(lv[0], lv[1], lv[2], lv[3]);
    }
}

// ---------------- mfma_top2: 256x256 tile, 8-phase counted-vmcnt pipeline + fused top-2 ----------------
// 8 waves (2M x 4N), per-wave 128x64 output. K = 12 tiles of 64 (3 products x 4 kt).
// Half-tile stream h=0..47: per K-tile T: {A-k0, B-k0, A-k1, B-k1}, each 16 KB
// (2 subtiles), staged into 8 rotating LDS slots (h&7). Phase p in [0,48):
//   stage h=p+4 (2 gload_lds/thr) ; vmcnt(6) counted (3 half-tiles in flight,
//   never 0 mid-loop) ; s_barrier ; ds_read a[4](+b[4]) ; lgkm0+sched_barrier ;
//   16 MFMA (setprio). Slot-reuse distance 8 with >=3 barriers between last
//   read (phase h+1) and overwrite issue (phase h+4): race-free.
__global__ __launch_bounds__(512, 2) void mfma_top2_kernel(
    const char* __restrict__ Ag, const char* __restrict__ Bg,
    const float* __restrict__ esq, float4* __restrict__ top2)
{
    __shared__ char lds[8 * 16384];   // 128 KB: 8 half-tile slots
    const int t = threadIdx.x;        // 0..511
    const int w = t >> 6, l = t & 63;
    const int wr = w >> 2, wc = w & 3;   // wave grid 2(M) x 4(N)
    const int nb = blockIdx.x;        // 0..15  (code-tile, fast axis)
    const int mb = blockIdx.y;        // 0..127 (row-tile)
    const int lh = l >> 4, ll = l & 15;

    // hoisted swizzled LDS offsets within a half-tile (subtile g*8192 + row*64B ^ swz)
    int aoff[8], boff[4];
#pragma unroll
    for (int i = 0; i < 8; ++i) {
        const int r = i * 16 + ll;                  // row within 128-row subtile
        aoff[i] = wr * 8192 + ((r * 64 + lh * 16) ^ ROWSWZ(r));
    }
#pragma unroll
    for (int j = 0; j < 4; ++j) {
        const int cr = (wc & 1) * 64 + j * 16 + ll; // col within 128-col subtile
        boff[j] = (wc >> 1) * 8192 + ((cr * 64 + lh * 16) ^ ROWSWZ(cr));
    }

    const char* Abase = Ag + (size_t)(2 * mb) * 131072;   // two 128-row mtiles
    const char* Bbase = Bg + (size_t)(2 * nb) * 131072;   // two 128-col ntiles

    f32x4 acc[8][4];
#pragma unroll
    for (int i = 0; i < 8; ++i)
#pragma unroll
        for (int j = 0; j < 4; ++j) acc[i][j] = 0.f;

    // half-tile h: T=h>>2 (K-tile), part=h&3 (0:A-k0 1:B-k0 2:A-k1 3:B-k1)
    // K-tile T: product p=T>>2 (0:HH 1:LH 2:HL), kt=T&3
#define STAGE_HT(H) do {                                                       \
        const int T_ = (H) >> 2, part_ = (H) & 3;                              \
        const int p_ = T_ >> 2, kt_ = T_ & 3, kh_ = part_ >> 1;                \
        const int isB_ = part_ & 1;                                            \
        const int sub_ = kt_ * 2 + kh_ + ((isB_ ? (p_ == 2) : (p_ == 1)) ? 8 : 0); \
        const char* src_ = isB_ ? Bbase : Abase;                               \
        char* dst_ = lds + ((H) & 7) * 16384;                                  \
        gload_lds16(src_ + sub_ * 8192 + t * 16,          dst_ + t * 16);      \
        gload_lds16(src_ + 131072 + sub_ * 8192 + t * 16, dst_ + 8192 + t * 16); \
    } while (0)

    // prologue: 4 half-tiles in flight
    STAGE_HT(0); STAGE_HT(1); STAGE_HT(2); STAGE_HT(3);

    bf16x8 bfr[4];
#pragma unroll
    for (int ph = 0; ph < 48; ++ph) {
        if (ph < 44) {
            STAGE_HT(ph + 4);
            asm volatile("s_waitcnt vmcnt(6)" ::: "memory");
        } else if (ph == 44) {
            asm volatile("s_waitcnt vmcnt(4)" ::: "memory");
        } else if (ph == 45) {
            asm volatile("s_waitcnt vmcnt(2)" ::: "memory");
        } else {
            asm volatile("s_waitcnt vmcnt(0)" ::: "memory");
        }
        __builtin_amdgcn_s_barrier();   // all waves' h <= ph+1 landed

        const int T = ph >> 2, kh = (ph >> 1) & 1, ch = ph & 1;
        const char* lA = lds + ((4 * T + 2 * kh) & 7) * 16384;
        const char* lB = lds + ((4 * T + 2 * kh + 1) & 7) * 16384;
        if (ch == 0) {
#pragma unroll
            for (int j = 0; j < 4; ++j) bfr[j] = *(const bf16x8*)(lB + boff[j]);
        }
        bf16x8 af[4];
#pragma unroll
        for (int ii = 0; ii < 4; ++ii) af[ii] = *(const bf16x8*)(lA + aoff[ch * 4 + ii]);
        asm volatile("s_waitcnt lgkmcnt(0)" ::: "memory");
        __builtin_amdgcn_sched_barrier(0);
        __builtin_amdgcn_s_setprio(1);
#pragma unroll
        for (int ii = 0; ii < 4; ++ii)
#pragma unroll
            for (int j = 0; j < 4; ++j)
                acc[ch * 4 + ii][j] = __builtin_amdgcn_mfma_f32_16x16x32_bf16(af[ii], bfr[j], acc[ch * 4 + ii][j], 0, 0, 0);
        __builtin_amdgcn_s_setprio(0);
    }
#undef STAGE_HT

    // epilogue: per-row top2 over this wave's 64 cols, in two 64-row halves.
    // C layout: col = ll, row = lh*4 + reg (within each 16x16 tile)
    const int colg0 = nb * 256 + wc * 64 + ll;
    const int cc = nb * 4 + wc;
#pragma unroll
    for (int ih = 0; ih < 2; ++ih) {
        float b1[16], b2[16];
        int k1[16];
#pragma unroll
        for (int q = 0; q < 16; ++q) { b1[q] = 3.4e38f; b2[q] = 3.4e38f; k1[q] = 0; }
#pragma unroll
        for (int j = 0; j < 4; ++j) {
            const int kcol = colg0 + j * 16;
            const float eq = esq[kcol];
#pragma unroll
            for (int ii = 0; ii < 4; ++ii)
#pragma unroll
                for (int r = 0; r < 4; ++r) {
                    const float s = fmaf(-2.f, acc[ih * 4 + ii][j][r], eq);
                    const int q = ii * 4 + r;
                    if (s < b1[q]) { b2[q] = b1[q]; b1[q] = s; k1[q] = kcol; }
                    else if (s < b2[q]) { b2[q] = s; }
                }
        }
        // merge the 16 col-lanes (masks 1,2,4,8 stay within the 16-lane group)
#pragma unroll
        for (int msk = 1; msk <= 8; msk <<= 1) {
#pragma unroll
            for (int q = 0; q < 16; ++q) {
                const float ob1 = __shfl_xor(b1[q], msk, 64);
                const int   ok1 = __shfl_xor(k1[q], msk, 64);
                const float ob2 = __shfl_xor(b2[q], msk, 64);
                if (ob1 < b1[q] || (ob1 == b1[q] && ok1 < k1[q])) {
                    b2[q] = fminf(b1[q], ob2); b1[q] = ob1; k1[q] = ok1;
                } else {
                    b2[q] = fminf(b2[q], ob1);
                }
            }
        }
        if (ll == 0) {
#pragma unroll
            for (int q = 0; q < 16; ++q) {
                const int ii = q >> 2, r = q & 3;
                const int row = mb * 256 + wr * 128 + ih * 64 + ii * 16 + lh * 4 + r;
                top2[(size_t)cc * NROWS + row] = make_float4(b1[q], __int_as_float(k1[q]), b2[q], 0.f);
            }
        }
    }
}

// ---------------- reduce: merge 64 col-chunks per row; compact ambiguous rows ----------------
__global__ __launch_bounds__(256) void reduce_top2_kernel(const float4* __restrict__ top2,
                                                          int* __restrict__ bidx,
                                                          int* __restrict__ flags,
                                                          int* __restrict__ list,
                                                          unsigned long long* __restrict__ res,
                                                          int* __restrict__ cnt) {
    const int row = blockIdx.x * 256 + threadIdx.x;
    float b1 = 3.4e38f, b2 = 3.4e38f;
    int k1 = 0x7fffffff;
#pragma unroll 8
    for (int c = 0; c < 64; ++c) {
        const float4 v = top2[(size_t)c * NROWS + row];
        const float ob1 = v.x, ob2 = v.z;
        const int ok1 = __float_as_int(v.y);
        if (ob1 < b1 || (ob1 == b1 && ok1 < k1)) { b2 = fminf(b1, ob2); b1 = ob1; k1 = ok1; }
        else { b2 = fminf(b2, ob1); }
    }
    bidx[row] = k1;
    const int f = (b2 - b1 <= DELTA) ? 1 : 0;
    flags[row] = f;
    if (f) {
        res[row] = ~0ULL;
        const int slot = atomicAdd(cnt, 1);
        list[slot] = row;
    }
}

// ---------------- rescore8: exact fp32 rescore, 8 rows x 256-code chunk per block ----------------
__global__ __launch_bounds__(256) void rescore8_kernel(const float* __restrict__ x,
                                                       const float* __restrict__ emb,
                                                       const float* __restrict__ esq,
                                                       const int* __restrict__ list,
                                                       const int* __restrict__ cnt,
                                                       unsigned long long* __restrict__ res) {
    __shared__ float xs[8][CCH];
    __shared__ int rid[8];
    const int t = threadIdx.x;
    const int q = blockIdx.x & 15;            // code chunk
    const int eg = blockIdx.x >> 4;           // entry group
    const int count = *cnt;
    const int k = q * 256 + t;
    const float eq = esq[k];
    const float* ek = emb + (size_t)k * CCH;

    for (int e8 = eg * 8; e8 < count; e8 += 128 * 8) {
        if (t < 8) rid[t] = (e8 + t < count) ? list[e8 + t] : -1;
        __syncthreads();
#pragma unroll
        for (int r = 0; r < 8; ++r) {
            const int rr = rid[r];
            if (rr >= 0) {
                const int b = rr >> 10, p = rr & 1023;
                xs[r][t] = x[((size_t)b * CCH + t) * N_PIX + p];
            }
        }
        __syncthreads();

        float dot[8];
#pragma unroll
        for (int r = 0; r < 8; ++r) dot[r] = 0.f;
#pragma unroll 8
        for (int c4 = 0; c4 < 64; ++c4) {
            const float4 e4 = *(const float4*)(ek + c4 * 4);
#pragma unroll
            for (int r = 0; r < 8; ++r) {
                const float4 xv = *(const float4*)(&xs[r][c4 * 4]);
                dot[r] = fmaf(xv.x, e4.x, dot[r]);
                dot[r] = fmaf(xv.y, e4.y, dot[r]);
                dot[r] = fmaf(xv.z, e4.z, dot[r]);
                dot[r] = fmaf(xv.w, e4.w, dot[r]);
            }
        }
#pragma unroll
        for (int r = 0; r < 8; ++r) {
            const float s = fmaf(-2.f, dot[r], eq);
            unsigned long long key = (((unsigned long long)mono(s)) << 32) | (unsigned)k;
#pragma unroll
            for (int off = 32; off > 0; off >>= 1) {
                const unsigned long long ok = __shfl_xor(key, off, 64);
                if (ok < key) key = ok;
            }
            if ((t & 63) == 0 && rid[r] >= 0)
                atomicMin(&res[rid[r]], key);
        }
        __syncthreads();
    }
}

// ---------------- apply: copy resolved indices for flagged rows ----------------
__global__ __launch_bounds__(256) void apply_kernel(const int* __restrict__ flags,
                                                    const unsigned long long* __restrict__ res,
                                                    int* __restrict__ bidx) {
    const int row = blockIdx.x * 256 + threadIdx.x;
    if (flags[row]) bidx[row] = (int)(res[row] & 0xFFFFFFFFULL);
}

// ---------------- fallback fp32 argmin (known-good) if ws too small ----------------
#define BROWS 32
#define FKTILE 256
#define FDCH 16
__global__ __launch_bounds__(256, 2) void argmin_fb_kernel(
    const float* __restrict__ x, const float* __restrict__ emb,
    const float* __restrict__ esq, int* __restrict__ bidx)
{
    __shared__ float xs[CCH * BROWS];
    __shared__ float es[FDCH * FKTILE];
    const int t = threadIdx.x;
    const int w = t >> 6;
    const int l = t & 63;
    const int n0 = blockIdx.x * BROWS;
    const int b = n0 >> 10;
    const int pixbase = n0 & (N_PIX - 1);
    const float* xb = x + (size_t)b * CCH * N_PIX + pixbase;
    {
        const int p4 = (t & 7) * 4;
        const int crow = t >> 3;
#pragma unroll
        for (int i = 0; i < 8; ++i) {
            const int c = i * 32 + crow;
            *(float4*)(xs + c * BROWS + p4) = *(const float4*)(xb + (size_t)c * N_PIX + p4);
        }
    }
    float best[8]; int bk[8];
#pragma unroll
    for (int r = 0; r < 8; ++r) { best[r] = 3.4e38f; bk[r] = 0; }
    float acc[8][4];
#pragma unroll
    for (int r = 0; r < 8; ++r)
#pragma unroll
        for (int j = 0; j < 4; ++j) acc[r][j] = 0.f;
    for (int kt = 0; kt < KCODES / FKTILE; ++kt) {
        for (int dc = 0; dc < CCH / FDCH; ++dc) {
            __syncthreads();
            {
                const float* src = emb + (size_t)(kt * FKTILE + t) * CCH + dc * FDCH;
#pragma unroll
                for (int c = 0; c < FDCH; ++c) es[c * FKTILE + t] = src[c];
            }
            __syncthreads();
            const int c0 = dc * FDCH;
            const float* ep = es + 4 * l;
            const float* xp = xs + c0 * BROWS + w * 8;
#pragma unroll
            for (int c = 0; c < FDCH; ++c) {
                const float4 ev = *(const float4*)(ep + c * FKTILE);
                const float4 xa = *(const float4*)(xp + c * BROWS);
                const float4 xc = *(const float4*)(xp + c * BROWS + 4);
                const float xr8[8] = {xa.x, xa.y, xa.z, xa.w, xc.x, xc.y, xc.z, xc.w};
#pragma unroll
                for (int r = 0; r < 8; ++r) {
                    acc[r][0] = fmaf(xr8[r], ev.x, acc[r][0]);
                    acc[r][1] = fmaf(xr8[r], ev.y, acc[r][1]);
                    acc[r][2] = fmaf(xr8[r], ev.z, acc[r][2]);
                    acc[r][3] = fmaf(xr8[r], ev.w, acc[r][3]);
                }
            }
        }
        const float4 q = *(const float4*)(esq + kt * FKTILE + 4 * l);
        const float qr[4] = {q.x, q.y, q.z, q.w};
#pragma unroll
        for (int r = 0; r < 8; ++r)
#pragma unroll
            for (int j = 0; j < 4; ++j) {
                const float s = fmaf(-2.f, acc[r][j], qr[j]);
                if (s < best[r]) { best[r] = s; bk[r] = kt * FKTILE + 4 * l + j; }
                acc[r][j] = 0.f;
            }
    }
#pragma unroll
    for (int r = 0; r < 8; ++r) {
        float bv = best[r]; int bi = bk[r];
#pragma unroll
        for (int off = 32; off > 0; off >>= 1) {
            const float ov = __shfl_xor(bv, off, 64);
            const int   oi = __shfl_xor(bi, off, 64);
            if (ov < bv || (ov == bv && oi < bi)) { bv = ov; bi = oi; }
        }
        if (l == 0) bidx[n0 + w * 8 + r] = bi;
    }
}

// ---------------- gather + oup + loss partials ----------------
__global__ __launch_bounds__(256) void gather_kernel(
    const float* __restrict__ x, const float* __restrict__ emb,
    const int* __restrict__ bidx, float* __restrict__ oup,
    float* __restrict__ partial)
{
    __shared__ int sidx[64];
    __shared__ float red[256];
    const int t = threadIdx.x;
    const int n0 = blockIdx.x * 64;
    const int b = n0 >> 10;
    const int pixbase = n0 & (N_PIX - 1);
    if (t < 64) sidx[t] = bidx[n0 + t];
    __syncthreads();
    const int pl = t & 63;
    const int w = t >> 6;
    const int k = sidx[pl];
    const float* xbp = x + (size_t)b * CCH * N_PIX + pixbase + pl;
    float* ob = oup + (size_t)b * CCH * N_PIX + pixbase + pl;
    const float* ek = emb + (size_t)k * CCH + w * 64;
    float lsum = 0.f;
#pragma unroll 4
    for (int cc = 0; cc < 16; ++cc) {
        const float4 e4 = *(const float4*)(ek + cc * 4);
        const float er[4] = {e4.x, e4.y, e4.z, e4.w};
#pragma unroll
        for (int j = 0; j < 4; ++j) {
            const size_t off = (size_t)(w * 64 + cc * 4 + j) * N_PIX;
            const float xv = xbp[off];
            ob[off] = er[j];
            const float d = xv - er[j];
            lsum = fmaf(d, d, lsum);
        }
    }
    red[t] = lsum;
    __syncthreads();
#pragma unroll
    for (int s = 128; s > 0; s >>= 1) {
        if (t < s) red[t] += red[t + s];
        __syncthreads();
    }
    if (t == 0) partial[blockIdx.x] = red[0];
}

__global__ __launch_bounds__(256) void finalize_kernel(const float* __restrict__ partial,
                                                       float* __restrict__ out_losses) {
    __shared__ float red[256];
    const int t = threadIdx.x;
    red[t] = partial[t] + partial[t + 256];
    __syncthreads();
    for (int s = 128; s > 0; s >>= 1) {
        if (t < s) red[t] += red[t + s];
        __syncthreads();
    }
    if (t == 0) {
        const float loss = red[0] * (1.0f / 8388608.0f);
        out_losses[0] = loss;
        out_losses[1] = loss;
    }
}

extern "C" void kernel_launch(void* const* d_in, const int* in_sizes, int n_in,
                              void* d_out, int out_size, void* d_ws, size_t ws_size,
                              hipStream_t stream) {
    const float* x = (const float*)d_in[0];
    const float* emb = (const float*)d_in[1];
    float* out = (float*)d_out;

    char* ws = (char*)d_ws;
    float* esq = (float*)(ws + OFF_ESQ);
    int* bidx = (int*)(ws + OFF_BIDX);
    int* flags = (int*)(ws + OFF_FLAGS);
    float* partial = (float*)(ws + OFF_PART);

    esq_kernel<<<KCODES / 4, 256, 0, stream>>>(emb, esq);

    if (ws_size >= (size_t)WS_NEEDED) {
        float4* top2 = (float4*)(ws + OFF_TOP2);
        char* A = ws + OFF_A;
        char* B = ws + OFF_B;
        int* list = (int*)(ws + OFF_LIST);
        unsigned long long* res = (unsigned long long*)(ws + OFF_RES);
        int* cnt = (int*)(ws + OFF_CNT);
        conv_x_kernel<<<NROWS / 64, 256, 0, stream>>>(x, A);
        conv_e_kernel<<<KCODES / 64, 256, 0, stream>>>(emb, B, cnt);
        mfma_top2_kernel<<<dim3(KCODES / 256, NROWS / 256), 512, 0, stream>>>(A, B, esq, top2);
        reduce_top2_kernel<<<NROWS / 256, 256, 0, stream>>>(top2, bidx, flags, list, res, cnt);
        rescore8_kernel<<<2048, 256, 0, stream>>>(x, emb, esq, list, cnt, res);
        apply_kernel<<<NROWS / 256, 256, 0, stream>>>(flags, res, bidx);
    } else {
        argmin_fb_kernel<<<NROWS / BROWS, 256, 0, stream>>>(x, emb, esq, bidx);
    }

    gather_kernel<<<NROWS / 64, 256, 0, stream>>>(x, emb, bidx, out, partial);
    finalize_kernel<<<1, 256, 0, stream>>>(partial, out + 8388608);
}

// Round 17
// 665.435 us; speedup vs baseline: 1.0016x; 1.0016x over previous
//
#include <hip/hip_runtime.h>

#define N_PIX 1024      // 32*32 pixels per image
#define BATCH 32
#define CCH 256         // channels == code dim
#define KCODES 4096
#define NROWS 32768     // BATCH * N_PIX
#define DELTA 0.0625f   // rescore margin (approx-score error bound ~0.003 typ, 0.05 worst)

typedef __attribute__((ext_vector_type(8))) short bf16x8;
typedef __attribute__((ext_vector_type(4))) float f32x4;

// ---- ws layout (bytes) ----
#define OFF_ESQ   0u
#define OFF_BIDX  16384u
#define OFF_FLAGS 147456u
#define OFF_PART  278528u
#define OFF_TOP2  524288u                    // 64 chunks x 32768 rows x float4 = 32 MB
#define OFF_A     34078720u                  // 256 mtiles(128r) x 16 sub x 8 KB = 32 MB (subtile, pre-swizzled)
#define OFF_B     67633152u                  // 32 ntiles(128r) x 16 sub x 8 KB = 4 MB (subtile, pre-swizzled)
#define WS_NEEDED 71827456u
// list/res/cnt live INSIDE the A region (dead after mfma_top2; rewritten every call by conv_x first)
#define OFF_LIST  OFF_A                      // 32768 i32 = 128 KB
#define OFF_RES   (OFF_A + 131072u)          // 32768 u64 = 256 KB
#define OFF_CNT   (OFF_A + 131072u + 262144u)

// swizzle for 64-B rows: spreads 16-lane b128 quarters over all 8 bank-groups
// per 8 rows. Applied at conv (pre-swizzled global) + ds_read (same involution).
#define ROWSWZ(row) ((((row) >> 1) & 3) << 4)

// round-to-nearest-even fp32 -> bf16 bits
__device__ __forceinline__ unsigned short f2bf(float v) {
    unsigned u = __float_as_uint(v);
    return (unsigned short)((u + 0x7FFFu + ((u >> 16) & 1u)) >> 16);
}
__device__ __forceinline__ float bf2f(unsigned short h) {
    return __uint_as_float(((unsigned)h) << 16);
}
// monotone float -> uint (total order preserving)
__device__ __forceinline__ unsigned mono(float s) {
    unsigned u = __float_as_uint(s);
    return (u & 0x80000000u) ? ~u : (u | 0x80000000u);
}

__device__ __forceinline__ void gload_lds16(const void* g, void* l) {
    __builtin_amdgcn_global_load_lds(
        (const __attribute__((address_space(1))) unsigned int*)g,
        (__attribute__((address_space(3))) unsigned int*)l, 16, 0, 0);
}

// ---------------- kernel 0: e_sq[k] = sum_c emb[k][c]^2 (exact fp32) ----------------
__global__ __launch_bounds__(256) void esq_kernel(const float* __restrict__ emb,
                                                  float* __restrict__ esq) {
    const int t = threadIdx.x;
    const int w = t >> 6, l = t & 63;
    const int k = blockIdx.x * 4 + w;
    const float4 v = *(const float4*)(emb + (size_t)k * CCH + l * 4);
    float s = v.x * v.x + v.y * v.y + v.z * v.z + v.w * v.w;
#pragma unroll
    for (int off = 32; off > 0; off >>= 1) s += __shfl_down(s, off);
    if (l == 0) esq[k] = s;
}

// ---------------- conv_x: x fp32 NCHW -> interleaved pre-swizzled bf16 hi/lo subtiles ----------------
// A[mtile128][sub 16][128 rows x 64 B]; sub = kt*2+half (hi), +8 (lo). 128 KB/mtile.
__global__ __launch_bounds__(256) void conv_x_kernel(const float* __restrict__ x,
                                                     char* __restrict__ A) {
    const int t = threadIdx.x;
    const int m = blockIdx.x * 64 + (t & 63);
    const int kt = t >> 6;                       // 0..3
    const int b = m >> 10, p = m & 1023;
    const float* src = x + ((size_t)b * CCH + kt * 64) * N_PIX + p;
    const int row = m & 127;
    char* tbase = A + (size_t)(m >> 7) * 131072;   // 128 KB per mtile
    const int swz = ROWSWZ(row);
#pragma unroll
    for (int g = 0; g < 8; ++g) {
        unsigned hv[4], lv[4];
#pragma unroll
        for (int e2 = 0; e2 < 4; ++e2) {
            const float v0 = src[(size_t)(g * 8 + e2 * 2 + 0) * N_PIX];
            const float v1 = src[(size_t)(g * 8 + e2 * 2 + 1) * N_PIX];
            const unsigned short h0 = f2bf(v0), h1 = f2bf(v1);
            const unsigned short l0 = f2bf(v0 - bf2f(h0)), l1 = f2bf(v1 - bf2f(h1));
            hv[e2] = (unsigned)h0 | ((unsigned)h1 << 16);
            lv[e2] = (unsigned)l0 | ((unsigned)l1 << 16);
        }
        const int sub_hi = kt * 2 + (g >> 2);            // 0..7
        const int byte = (row * 64 + (g & 3) * 16) ^ swz;
        *(uint4*)(tbase + sub_hi * 8192 + byte)       = make_uint4(hv[0], hv[1], hv[2], hv[3]);
        *(uint4*)(tbase + (8 + sub_hi) * 8192 + byte) = make_uint4(lv[0], lv[1], lv[2], lv[3]);
    }
}

// ---------------- conv_e: embedding fp32 -> interleaved pre-swizzled bf16 hi/lo subtiles ----------------
__global__ __launch_bounds__(256) void conv_e_kernel(const float* __restrict__ emb,
                                                     char* __restrict__ B,
                                                     int* __restrict__ cnt) {
    const int t = threadIdx.x;
    if (blockIdx.x == 0 && t == 0) *cnt = 0;   // runs after conv_x (which clobbers this region)
    const int n = blockIdx.x * 64 + (t & 63);
    const int kt = t >> 6;
    const float* src = emb + (size_t)n * CCH + kt * 64;
    const int row = n & 127;
    char* tbase = B + (size_t)(n >> 7) * 131072;   // 128 KB per ntile
    const int swz = ROWSWZ(row);
#pragma unroll
    for (int g = 0; g < 8; ++g) {
        const float4 a = *(const float4*)(src + g * 8);
        const float4 c = *(const float4*)(src + g * 8 + 4);
        const float vr[8] = {a.x, a.y, a.z, a.w, c.x, c.y, c.z, c.w};
        unsigned hv[4], lv[4];
#pragma unroll
        for (int e2 = 0; e2 < 4; ++e2) {
            const unsigned short h0 = f2bf(vr[e2 * 2]), h1 = f2bf(vr[e2 * 2 + 1]);
            const unsigned short l0 = f2bf(vr[e2 * 2] - bf2f(h0));
            const unsigned short l1 = f2bf(vr[e2 * 2 + 1] - bf2f(h1));
            hv[e2] = (unsigned)h0 | ((unsigned)h1 << 16);
            lv[e2] = (unsigned)l0 | ((unsigned)l1 << 16);
        }
        const int sub_hi = kt * 2 + (g >> 2);
        const int byte = (row * 64 + (g & 3) * 16) ^ swz;
        *(uint4*)(tbase + sub_hi * 8192 + byte)       = make_uint4(hv[0], hv[1], hv[2], hv[3]);
        *(uint4*)(tbase + (8 + sub_hi) * 8192 + byte) = make_uint4(lv[0], lv[1], lv[2], lv[3]);
    }
}

// ---------------- mfma_top2: 256x256 tile, 8-phase counted-vmcnt pipeline + fused top-2 ----------------
// 8 waves (2M x 4N), per-wave 128x64 output. K = 12 tiles of 64 (3 products x 4 kt).
// Half-tile stream h=0..47; 8 rotating LDS slots; counted vmcnt(6); one barrier
// per phase; 16 MFMA per phase. __launch_bounds__(512,1): 256-reg budget (acc
// alone is 128 unified regs) -- (512,2) in R16 capped at 128 and spilled 78 MB.
__global__ __launch_bounds__(512, 1) void mfma_top2_kernel(
    const char* __restrict__ Ag, const char* __restrict__ Bg,
    const float* __restrict__ esq, float4* __restrict__ top2)
{
    __shared__ char lds[8 * 16384];   // 128 KB: 8 half-tile slots
    const int t = threadIdx.x;        // 0..511
    const int w = t >> 6, l = t & 63;
    const int wr = w >> 2, wc = w & 3;   // wave grid 2(M) x 4(N)
    const int nb = blockIdx.x;        // 0..15  (code-tile, fast axis)
    const int mb = blockIdx.y;        // 0..127 (row-tile)
    const int lh = l >> 4, ll = l & 15;

    // hoisted swizzled LDS offsets within a half-tile (subtile g*8192 + row*64B ^ swz)
    int aoff[8], boff[4];
#pragma unroll
    for (int i = 0; i < 8; ++i) {
        const int r = i * 16 + ll;                  // row within 128-row subtile
        aoff[i] = wr * 8192 + ((r * 64 + lh * 16) ^ ROWSWZ(r));
    }
#pragma unroll
    for (int j = 0; j < 4; ++j) {
        const int cr = (wc & 1) * 64 + j * 16 + ll; // col within 128-col subtile
        boff[j] = (wc >> 1) * 8192 + ((cr * 64 + lh * 16) ^ ROWSWZ(cr));
    }

    const char* Abase = Ag + (size_t)(2 * mb) * 131072;   // two 128-row mtiles
    const char* Bbase = Bg + (size_t)(2 * nb) * 131072;   // two 128-col ntiles

    f32x4 acc[8][4];
#pragma unroll
    for (int i = 0; i < 8; ++i)
#pragma unroll
        for (int j = 0; j < 4; ++j) acc[i][j] = 0.f;

    // half-tile h: T=h>>2 (K-tile), part=h&3 (0:A-k0 1:B-k0 2:A-k1 3:B-k1)
    // K-tile T: product p=T>>2 (0:HH 1:LH 2:HL), kt=T&3
#define STAGE_HT(H) do {                                                       \
        const int T_ = (H) >> 2, part_ = (H) & 3;                              \
        const int p_ = T_ >> 2, kt_ = T_ & 3, kh_ = part_ >> 1;                \
        const int isB_ = part_ & 1;                                            \
        const int sub_ = kt_ * 2 + kh_ + ((isB_ ? (p_ == 2) : (p_ == 1)) ? 8 : 0); \
        const char* src_ = isB_ ? Bbase : Abase;                               \
        char* dst_ = lds + ((H) & 7) * 16384;                                  \
        gload_lds16(src_ + sub_ * 8192 + t * 16,          dst_ + t * 16);      \
        gload_lds16(src_ + 131072 + sub_ * 8192 + t * 16, dst_ + 8192 + t * 16); \
    } while (0)

    // prologue: 4 half-tiles in flight
    STAGE_HT(0); STAGE_HT(1); STAGE_HT(2); STAGE_HT(3);

    bf16x8 bfr[4];
#pragma unroll
    for (int ph = 0; ph < 48; ++ph) {
        if (ph < 44) {
            STAGE_HT(ph + 4);
            asm volatile("s_waitcnt vmcnt(6)" ::: "memory");
        } else if (ph == 44) {
            asm volatile("s_waitcnt vmcnt(4)" ::: "memory");
        } else if (ph == 45) {
            asm volatile("s_waitcnt vmcnt(2)" ::: "memory");
        } else {
            asm volatile("s_waitcnt vmcnt(0)" ::: "memory");
        }
        __builtin_amdgcn_s_barrier();   // all waves' h <= ph+1 landed

        const int T = ph >> 2, kh = (ph >> 1) & 1, ch = ph & 1;
        const char* lA = lds + ((4 * T + 2 * kh) & 7) * 16384;
        const char* lB = lds + ((4 * T + 2 * kh + 1) & 7) * 16384;
        if (ch == 0) {
#pragma unroll
            for (int j = 0; j < 4; ++j) bfr[j] = *(const bf16x8*)(lB + boff[j]);
        }
        bf16x8 af[4];
#pragma unroll
        for (int ii = 0; ii < 4; ++ii) af[ii] = *(const bf16x8*)(lA + aoff[ch * 4 + ii]);
        asm volatile("s_waitcnt lgkmcnt(0)" ::: "memory");
        __builtin_amdgcn_sched_barrier(0);
        __builtin_amdgcn_s_setprio(1);
#pragma unroll
        for (int ii = 0; ii < 4; ++ii)
#pragma unroll
            for (int j = 0; j < 4; ++j)
                acc[ch * 4 + ii][j] = __builtin_amdgcn_mfma_f32_16x16x32_bf16(af[ii], bfr[j], acc[ch * 4 + ii][j], 0, 0, 0);
        __builtin_amdgcn_s_setprio(0);
    }
#undef STAGE_HT

    // epilogue: per-row top2 over this wave's 64 cols, in two 64-row halves.
    // C layout: col = ll, row = lh*4 + reg (within each 16x16 tile)
    const int colg0 = nb * 256 + wc * 64 + ll;
    const int cc = nb * 4 + wc;
#pragma unroll
    for (int ih = 0; ih < 2; ++ih) {
        float b1[16], b2[16];
        int k1[16];
#pragma unroll
        for (int q = 0; q < 16; ++q) { b1[q] = 3.4e38f; b2[q] = 3.4e38f; k1[q] = 0; }
#pragma unroll
        for (int j = 0; j < 4; ++j) {
            const int kcol = colg0 + j * 16;
            const float eq = esq[kcol];
#pragma unroll
            for (int ii = 0; ii < 4; ++ii)
#pragma unroll
                for (int r = 0; r < 4; ++r) {
                    const float s = fmaf(-2.f, acc[ih * 4 + ii][j][r], eq);
                    const int q = ii * 4 + r;
                    if (s < b1[q]) { b2[q] = b1[q]; b1[q] = s; k1[q] = kcol; }
                    else if (s < b2[q]) { b2[q] = s; }
                }
        }
        // merge the 16 col-lanes (masks 1,2,4,8 stay within the 16-lane group)
#pragma unroll
        for (int msk = 1; msk <= 8; msk <<= 1) {
#pragma unroll
            for (int q = 0; q < 16; ++q) {
                const float ob1 = __shfl_xor(b1[q], msk, 64);
                const int   ok1 = __shfl_xor(k1[q], msk, 64);
                const float ob2 = __shfl_xor(b2[q], msk, 64);
                if (ob1 < b1[q] || (ob1 == b1[q] && ok1 < k1[q])) {
                    b2[q] = fminf(b1[q], ob2); b1[q] = ob1; k1[q] = ok1;
                } else {
                    b2[q] = fminf(b2[q], ob1);
                }
            }
        }
        if (ll == 0) {
#pragma unroll
            for (int q = 0; q < 16; ++q) {
                const int ii = q >> 2, r = q & 3;
                const int row = mb * 256 + wr * 128 + ih * 64 + ii * 16 + lh * 4 + r;
                top2[(size_t)cc * NROWS + row] = make_float4(b1[q], __int_as_float(k1[q]), b2[q], 0.f);
            }
        }
    }
}

// ---------------- reduce: merge 64 col-chunks per row; compact ambiguous rows ----------------
__global__ __launch_bounds__(256) void reduce_top2_kernel(const float4* __restrict__ top2,
                                                          int* __restrict__ bidx,
                                                          int* __restrict__ flags,
                                                          int* __restrict__ list,
                                                          unsigned long long* __restrict__ res,
                                                          int* __restrict__ cnt) {
    const int row = blockIdx.x * 256 + threadIdx.x;
    float b1 = 3.4e38f, b2 = 3.4e38f;
    int k1 = 0x7fffffff;
#pragma unroll 8
    for (int c = 0; c < 64; ++c) {
        const float4 v = top2[(size_t)c * NROWS + row];
        const float ob1 = v.x, ob2 = v.z;
        const int ok1 = __float_as_int(v.y);
        if (ob1 < b1 || (ob1 == b1 && ok1 < k1)) { b2 = fminf(b1, ob2); b1 = ob1; k1 = ok1; }
        else { b2 = fminf(b2, ob1); }
    }
    bidx[row] = k1;
    const int f = (b2 - b1 <= DELTA) ? 1 : 0;
    flags[row] = f;
    if (f) {
        res[row] = ~0ULL;
        const int slot = atomicAdd(cnt, 1);
        list[slot] = row;
    }
}

// ---------------- rescore8: exact fp32 rescore, 8 rows x 256-code chunk per block ----------------
__global__ __launch_bounds__(256) void rescore8_kernel(const float* __restrict__ x,
                                                       const float* __restrict__ emb,
                                                       const float* __restrict__ esq,
                                                       const int* __restrict__ list,
                                                       const int* __restrict__ cnt,
                                                       unsigned long long* __restrict__ res) {
    __shared__ float xs[8][CCH];
    __shared__ int rid[8];
    const int t = threadIdx.x;
    const int q = blockIdx.x & 15;            // code chunk
    const int eg = blockIdx.x >> 4;           // entry group
    const int count = *cnt;
    const int k = q * 256 + t;
    const float eq = esq[k];
    const float* ek = emb + (size_t)k * CCH;

    for (int e8 = eg * 8; e8 < count; e8 += 128 * 8) {
        if (t < 8) rid[t] = (e8 + t < count) ? list[e8 + t] : -1;
        __syncthreads();
#pragma unroll
        for (int r = 0; r < 8; ++r) {
            const int rr = rid[r];
            if (rr >= 0) {
                const int b = rr >> 10, p = rr & 1023;
                xs[r][t] = x[((size_t)b * CCH + t) * N_PIX + p];
            }
        }
        __syncthreads();

        float dot[8];
#pragma unroll
        for (int r = 0; r < 8; ++r) dot[r] = 0.f;
#pragma unroll 8
        for (int c4 = 0; c4 < 64; ++c4) {
            const float4 e4 = *(const float4*)(ek + c4 * 4);
#pragma unroll
            for (int r = 0; r < 8; ++r) {
                const float4 xv = *(const float4*)(&xs[r][c4 * 4]);
                dot[r] = fmaf(xv.x, e4.x, dot[r]);
                dot[r] = fmaf(xv.y, e4.y, dot[r]);
                dot[r] = fmaf(xv.z, e4.z, dot[r]);
                dot[r] = fmaf(xv.w, e4.w, dot[r]);
            }
        }
#pragma unroll
        for (int r = 0; r < 8; ++r) {
            const float s = fmaf(-2.f, dot[r], eq);
            unsigned long long key = (((unsigned long long)mono(s)) << 32) | (unsigned)k;
#pragma unroll
            for (int off = 32; off > 0; off >>= 1) {
                const unsigned long long ok = __shfl_xor(key, off, 64);
                if (ok < key) key = ok;
            }
            if ((t & 63) == 0 && rid[r] >= 0)
                atomicMin(&res[rid[r]], key);
        }
        __syncthreads();
    }
}

// ---------------- apply: copy resolved indices for flagged rows ----------------
__global__ __launch_bounds__(256) void apply_kernel(const int* __restrict__ flags,
                                                    const unsigned long long* __restrict__ res,
                                                    int* __restrict__ bidx) {
    const int row = blockIdx.x * 256 + threadIdx.x;
    if (flags[row]) bidx[row] = (int)(res[row] & 0xFFFFFFFFULL);
}

// ---------------- fallback fp32 argmin (known-good) if ws too small ----------------
#define BROWS 32
#define FKTILE 256
#define FDCH 16
__global__ __launch_bounds__(256, 2) void argmin_fb_kernel(
    const float* __restrict__ x, const float* __restrict__ emb,
    const float* __restrict__ esq, int* __restrict__ bidx)
{
    __shared__ float xs[CCH * BROWS];
    __shared__ float es[FDCH * FKTILE];
    const int t = threadIdx.x;
    const int w = t >> 6;
    const int l = t & 63;
    const int n0 = blockIdx.x * BROWS;
    const int b = n0 >> 10;
    const int pixbase = n0 & (N_PIX - 1);
    const float* xb = x + (size_t)b * CCH * N_PIX + pixbase;
    {
        const int p4 = (t & 7) * 4;
        const int crow = t >> 3;
#pragma unroll
        for (int i = 0; i < 8; ++i) {
            const int c = i * 32 + crow;
            *(float4*)(xs + c * BROWS + p4) = *(const float4*)(xb + (size_t)c * N_PIX + p4);
        }
    }
    float best[8]; int bk[8];
#pragma unroll
    for (int r = 0; r < 8; ++r) { best[r] = 3.4e38f; bk[r] = 0; }
    float acc[8][4];
#pragma unroll
    for (int r = 0; r < 8; ++r)
#pragma unroll
        for (int j = 0; j < 4; ++j) acc[r][j] = 0.f;
    for (int kt = 0; kt < KCODES / FKTILE; ++kt) {
        for (int dc = 0; dc < CCH / FDCH; ++dc) {
            __syncthreads();
            {
                const float* src = emb + (size_t)(kt * FKTILE + t) * CCH + dc * FDCH;
#pragma unroll
                for (int c = 0; c < FDCH; ++c) es[c * FKTILE + t] = src[c];
            }
            __syncthreads();
            const int c0 = dc * FDCH;
            const float* ep = es + 4 * l;
            const float* xp = xs + c0 * BROWS + w * 8;
#pragma unroll
            for (int c = 0; c < FDCH; ++c) {
                const float4 ev = *(const float4*)(ep + c * FKTILE);
                const float4 xa = *(const float4*)(xp + c * BROWS);
                const float4 xc = *(const float4*)(xp + c * BROWS + 4);
                const float xr8[8] = {xa.x, xa.y, xa.z, xa.w, xc.x, xc.y, xc.z, xc.w};
#pragma unroll
                for (int r = 0; r < 8; ++r) {
                    acc[r][0] = fmaf(xr8[r], ev.x, acc[r][0]);
                    acc[r][1] = fmaf(xr8[r], ev.y, acc[r][1]);
                    acc[r][2] = fmaf(xr8[r], ev.z, acc[r][2]);
                    acc[r][3] = fmaf(xr8[r], ev.w, acc[r][3]);
                }
            }
        }
        const float4 q = *(const float4*)(esq + kt * FKTILE + 4 * l);
        const float qr[4] = {q.x, q.y, q.z, q.w};
#pragma unroll
        for (int r = 0; r < 8; ++r)
#pragma unroll
            for (int j = 0; j < 4; ++j) {
                const float s = fmaf(-2.f, acc[r][j], qr[j]);
                if (s < best[r]) { best[r] = s; bk[r] = kt * FKTILE + 4 * l + j; }
                acc[r][j] = 0.f;
            }
    }
#pragma unroll
    for (int r = 0; r < 8; ++r) {
        float bv = best[r]; int bi = bk[r];
#pragma unroll
        for (int off = 32; off > 0; off >>= 1) {
            const float ov = __shfl_xor(bv, off, 64);
            const int   oi = __shfl_xor(bi, off, 64);
            if (ov < bv || (ov == bv && oi < bi)) { bv = ov; bi = oi; }
        }
        if (l == 0) bidx[n0 + w * 8 + r] = bi;
    }
}

// ---------------- gather + oup + loss partials ----------------
__global__ __launch_bounds__(256) void gather_kernel(
    const float* __restrict__ x, const float* __restrict__ emb,
    const int* __restrict__ bidx, float* __restrict__ oup,
    float* __restrict__ partial)
{
    __shared__ int sidx[64];
    __shared__ float red[256];
    const int t = threadIdx.x;
    const int n0 = blockIdx.x * 64;
    const int b = n0 >> 10;
    const int pixbase = n0 & (N_PIX - 1);
    if (t < 64) sidx[t] = bidx[n0 + t];
    __syncthreads();
    const int pl = t & 63;
    const int w = t >> 6;
    const int k = sidx[pl];
    const float* xbp = x + (size_t)b * CCH * N_PIX + pixbase + pl;
    float* ob = oup + (size_t)b * CCH * N_PIX + pixbase + pl;
    const float* ek = emb + (size_t)k * CCH + w * 64;
    float lsum = 0.f;
#pragma unroll 4
    for (int cc = 0; cc < 16; ++cc) {
        const float4 e4 = *(const float4*)(ek + cc * 4);
        const float er[4] = {e4.x, e4.y, e4.z, e4.w};
#pragma unroll
        for (int j = 0; j < 4; ++j) {
            const size_t off = (size_t)(w * 64 + cc * 4 + j) * N_PIX;
            const float xv = xbp[off];
            ob[off] = er[j];
            const float d = xv - er[j];
            lsum = fmaf(d, d, lsum);
        }
    }
    red[t] = lsum;
    __syncthreads();
#pragma unroll
    for (int s = 128; s > 0; s >>= 1) {
        if (t < s) red[t] += red[t + s];
        __syncthreads();
    }
    if (t == 0) partial[blockIdx.x] = red[0];
}

__global__ __launch_bounds__(256) void finalize_kernel(const float* __restrict__ partial,
                                                       float* __restrict__ out_losses) {
    __shared__ float red[256];
    const int t = threadIdx.x;
    red[t] = partial[t] + partial[t + 256];
    __syncthreads();
    for (int s = 128; s > 0; s >>= 1) {
        if (t < s) red[t] += red[t + s];
        __syncthreads();
    }
    if (t == 0) {
        const float loss = red[0] * (1.0f / 8388608.0f);
        out_losses[0] = loss;
        out_losses[1] = loss;
    }
}

extern "C" void kernel_launch(void* const* d_in, const int* in_sizes, int n_in,
                              void* d_out, int out_size, void* d_ws, size_t ws_size,
                              hipStream_t stream) {
    const float* x = (const float*)d_in[0];
    const float* emb = (const float*)d_in[1];
    float* out = (float*)d_out;

    char* ws = (char*)d_ws;
    float* esq = (float*)(ws + OFF_ESQ);
    int* bidx = (int*)(ws + OFF_BIDX);
    int* flags = (int*)(ws + OFF_FLAGS);
    float* partial = (float*)(ws + OFF_PART);

    esq_kernel<<<KCODES / 4, 256, 0, stream>>>(emb, esq);

    if (ws_size >= (size_t)WS_NEEDED) {
        float4* top2 = (float4*)(ws + OFF_TOP2);
        char* A = ws + OFF_A;
        char* B = ws + OFF_B;
        int* list = (int*)(ws + OFF_LIST);
        unsigned long long* res = (unsigned long long*)(ws + OFF_RES);
        int* cnt = (int*)(ws + OFF_CNT);
        conv_x_kernel<<<NROWS / 64, 256, 0, stream>>>(x, A);
        conv_e_kernel<<<KCODES / 64, 256, 0, stream>>>(emb, B, cnt);
        mfma_top2_kernel<<<dim3(KCODES / 256, NROWS / 256), 512, 0, stream>>>(A, B, esq, top2);
        reduce_top2_kernel<<<NROWS / 256, 256, 0, stream>>>(top2, bidx, flags, list, res, cnt);
        rescore8_kernel<<<2048, 256, 0, stream>>>(x, emb, esq, list, cnt, res);
        apply_kernel<<<NROWS / 256, 256, 0, stream>>>(flags, res, bidx);
    } else {
        argmin_fb_kernel<<<NROWS / BROWS, 256, 0, stream>>>(x, emb, esq, bidx);
    }

    gather_kernel<<<NROWS / 64, 256, 0, stream>>>(x, emb, bidx, out, partial);
    finalize_kernel<<<1, 256, 0, stream>>>(partial, out + 8388608);
}

// Round 18
// 414.937 us; speedup vs baseline: 1.6062x; 1.6037x over previous
//
#include <hip/hip_runtime.h>

#define N_PIX 1024      // 32*32 pixels per image
#define BATCH 32
#define CCH 256         // channels == code dim
#define KCODES 4096
#define NROWS 32768     // BATCH * N_PIX
#define DELTA 0.0625f   // rescore margin (approx-score error bound ~0.003 typ, 0.05 worst)

typedef __attribute__((ext_vector_type(8))) short bf16x8;
typedef __attribute__((ext_vector_type(4))) float f32x4;

// ---- ws layout (bytes) ----
#define OFF_ESQ   0u
#define OFF_BIDX  16384u
#define OFF_FLAGS 147456u
#define OFF_PART  278528u
#define OFF_TOP2  524288u                    // 64 chunks x 32768 rows x float4 = 32 MB
#define OFF_A     34078720u                  // 256 mtiles(128r) x 16 sub x 8 KB = 32 MB (subtile, pre-swizzled)
#define OFF_B     67633152u                  // 32 ntiles(128r) x 16 sub x 8 KB = 4 MB (subtile, pre-swizzled)
#define WS_NEEDED 71827456u
// list/res/cnt live INSIDE the A region (dead after mfma_top2; rewritten every call by conv_x first)
#define OFF_LIST  OFF_A                      // 32768 i32 = 128 KB
#define OFF_RES   (OFF_A + 131072u)          // 32768 u64 = 256 KB
#define OFF_CNT   (OFF_A + 131072u + 262144u)

// swizzle for 64-B rows: spreads 16-lane b128 quarters over all 8 bank-groups
// per 8 rows. Applied at conv (pre-swizzled global) + ds_read (same involution).
#define ROWSWZ(row) ((((row) >> 1) & 3) << 4)

// round-to-nearest-even fp32 -> bf16 bits
__device__ __forceinline__ unsigned short f2bf(float v) {
    unsigned u = __float_as_uint(v);
    return (unsigned short)((u + 0x7FFFu + ((u >> 16) & 1u)) >> 16);
}
__device__ __forceinline__ float bf2f(unsigned short h) {
    return __uint_as_float(((unsigned)h) << 16);
}
// monotone float -> uint (total order preserving)
__device__ __forceinline__ unsigned mono(float s) {
    unsigned u = __float_as_uint(s);
    return (u & 0x80000000u) ? ~u : (u | 0x80000000u);
}

__device__ __forceinline__ void gload_lds16(const void* g, void* l) {
    __builtin_amdgcn_global_load_lds(
        (const __attribute__((address_space(1))) unsigned int*)g,
        (__attribute__((address_space(3))) unsigned int*)l, 16, 0, 0);
}

// ---------------- kernel 0: e_sq[k] = sum_c emb[k][c]^2 (exact fp32) ----------------
__global__ __launch_bounds__(256) void esq_kernel(const float* __restrict__ emb,
                                                  float* __restrict__ esq) {
    const int t = threadIdx.x;
    const int w = t >> 6, l = t & 63;
    const int k = blockIdx.x * 4 + w;
    const float4 v = *(const float4*)(emb + (size_t)k * CCH + l * 4);
    float s = v.x * v.x + v.y * v.y + v.z * v.z + v.w * v.w;
#pragma unroll
    for (int off = 32; off > 0; off >>= 1) s += __shfl_down(s, off);
    if (l == 0) esq[k] = s;
}

// ---------------- conv_x: x fp32 NCHW -> interleaved pre-swizzled bf16 hi/lo subtiles ----------------
// A[mtile128][sub 16][128 rows x 64 B]; sub = kt*2+half (hi), +8 (lo). 128 KB/mtile.
__global__ __launch_bounds__(256) void conv_x_kernel(const float* __restrict__ x,
                                                     char* __restrict__ A) {
    const int t = threadIdx.x;
    const int m = blockIdx.x * 64 + (t & 63);
    const int kt = t >> 6;                       // 0..3
    const int b = m >> 10, p = m & 1023;
    const float* src = x + ((size_t)b * CCH + kt * 64) * N_PIX + p;
    const int row = m & 127;
    char* tbase = A + (size_t)(m >> 7) * 131072;   // 128 KB per mtile
    const int swz = ROWSWZ(row);
#pragma unroll
    for (int g = 0; g < 8; ++g) {
        unsigned hv[4], lv[4];
#pragma unroll
        for (int e2 = 0; e2 < 4; ++e2) {
            const float v0 = src[(size_t)(g * 8 + e2 * 2 + 0) * N_PIX];
            const float v1 = src[(size_t)(g * 8 + e2 * 2 + 1) * N_PIX];
            const unsigned short h0 = f2bf(v0), h1 = f2bf(v1);
            const unsigned short l0 = f2bf(v0 - bf2f(h0)), l1 = f2bf(v1 - bf2f(h1));
            hv[e2] = (unsigned)h0 | ((unsigned)h1 << 16);
            lv[e2] = (unsigned)l0 | ((unsigned)l1 << 16);
        }
        const int sub_hi = kt * 2 + (g >> 2);            // 0..7
        const int byte = (row * 64 + (g & 3) * 16) ^ swz;
        *(uint4*)(tbase + sub_hi * 8192 + byte)       = make_uint4(hv[0], hv[1], hv[2], hv[3]);
        *(uint4*)(tbase + (8 + sub_hi) * 8192 + byte) = make_uint4(lv[0], lv[1], lv[2], lv[3]);
    }
}

// ---------------- conv_e: embedding fp32 -> interleaved pre-swizzled bf16 hi/lo subtiles ----------------
__global__ __launch_bounds__(256) void conv_e_kernel(const float* __restrict__ emb,
                                                     char* __restrict__ B,
                                                     int* __restrict__ cnt) {
    const int t = threadIdx.x;
    if (blockIdx.x == 0 && t == 0) *cnt = 0;   // runs after conv_x (which clobbers this region)
    const int n = blockIdx.x * 64 + (t & 63);
    const int kt = t >> 6;
    const float* src = emb + (size_t)n * CCH + kt * 64;
    const int row = n & 127;
    char* tbase = B + (size_t)(n >> 7) * 131072;   // 128 KB per ntile
    const int swz = ROWSWZ(row);
#pragma unroll
    for (int g = 0; g < 8; ++g) {
        const float4 a = *(const float4*)(src + g * 8);
        const float4 c = *(const float4*)(src + g * 8 + 4);
        const float vr[8] = {a.x, a.y, a.z, a.w, c.x, c.y, c.z, c.w};
        unsigned hv[4], lv[4];
#pragma unroll
        for (int e2 = 0; e2 < 4; ++e2) {
            const unsigned short h0 = f2bf(vr[e2 * 2]), h1 = f2bf(vr[e2 * 2 + 1]);
            const unsigned short l0 = f2bf(vr[e2 * 2] - bf2f(h0));
            const unsigned short l1 = f2bf(vr[e2 * 2 + 1] - bf2f(h1));
            hv[e2] = (unsigned)h0 | ((unsigned)h1 << 16);
            lv[e2] = (unsigned)l0 | ((unsigned)l1 << 16);
        }
        const int sub_hi = kt * 2 + (g >> 2);
        const int byte = (row * 64 + (g & 3) * 16) ^ swz;
        *(uint4*)(tbase + sub_hi * 8192 + byte)       = make_uint4(hv[0], hv[1], hv[2], hv[3]);
        *(uint4*)(tbase + (8 + sub_hi) * 8192 + byte) = make_uint4(lv[0], lv[1], lv[2], lv[3]);
    }
}

// ---------------- mfma_top2: 256x256 tile, 8-phase counted-vmcnt pipeline + fused top-2 ----------------
// 8 waves (2M x 4N), per-wave 128x64 output. K = 12 tiles of 64 (3 products x 4 kt).
// Half-tile stream h=0..47; 8 rotating LDS slots; counted vmcnt(6); one barrier/phase.
// ROLLED outer T-loop (unroll 1) + peeled tail: phase-local live ranges keep arch
// VGPRs ~70 (R16/R17's full unroll stretched them past 128 -> 76 MB scratch spill).
__global__ __launch_bounds__(512, 1) void mfma_top2_kernel(
    const char* __restrict__ Ag, const char* __restrict__ Bg,
    const float* __restrict__ esq, float4* __restrict__ top2)
{
    __shared__ char lds[8 * 16384];   // 128 KB: 8 half-tile slots
    const int t = threadIdx.x;        // 0..511
    const int w = t >> 6, l = t & 63;
    const int wr = w >> 2, wc = w & 3;   // wave grid 2(M) x 4(N)
    const int nb = blockIdx.x;        // 0..15  (code-tile, fast axis)
    const int mb = blockIdx.y;        // 0..127 (row-tile)
    const int lh = l >> 4, ll = l & 15;

    // hoisted swizzled LDS offsets within a half-tile (subtile g*8192 + row*64B ^ swz)
    int aoff[8], boff[4];
#pragma unroll
    for (int i = 0; i < 8; ++i) {
        const int r = i * 16 + ll;                  // row within 128-row subtile
        aoff[i] = wr * 8192 + ((r * 64 + lh * 16) ^ ROWSWZ(r));
    }
#pragma unroll
    for (int j = 0; j < 4; ++j) {
        const int cr = (wc & 1) * 64 + j * 16 + ll; // col within 128-col subtile
        boff[j] = (wc >> 1) * 8192 + ((cr * 64 + lh * 16) ^ ROWSWZ(cr));
    }

    const char* Abase = Ag + (size_t)(2 * mb) * 131072;   // two 128-row mtiles
    const char* Bbase = Bg + (size_t)(2 * nb) * 131072;   // two 128-col ntiles

    f32x4 acc[8][4];
#pragma unroll
    for (int i = 0; i < 8; ++i)
#pragma unroll
        for (int j = 0; j < 4; ++j) acc[i][j] = 0.f;

    // half-tile h: T=h>>2 (K-tile), part=h&3 (0:A-k0 1:B-k0 2:A-k1 3:B-k1)
    // K-tile T: product p=T>>2 (0:HH 1:LH 2:HL), kt=T&3
#define STAGE_HT(H) do {                                                       \
        const int T_ = (H) >> 2, part_ = (H) & 3;                              \
        const int p_ = T_ >> 2, kt_ = T_ & 3, kh_ = part_ >> 1;                \
        const int isB_ = part_ & 1;                                            \
        const int sub_ = kt_ * 2 + kh_ + ((isB_ ? (p_ == 2) : (p_ == 1)) ? 8 : 0); \
        const char* src_ = isB_ ? Bbase : Abase;                               \
        char* dst_ = lds + ((H) & 7) * 16384;                                  \
        gload_lds16(src_ + sub_ * 8192 + t * 16,          dst_ + t * 16);      \
        gload_lds16(src_ + 131072 + sub_ * 8192 + t * 16, dst_ + 8192 + t * 16); \
    } while (0)

    // COMPUTE(TT, KH, CH): KH/CH compile-time; slot base runtime (scalar math).
#define COMPUTE(TT, KH, CH) do {                                               \
        const char* lA_ = lds + ((4 * (TT) + 2 * (KH)) & 7) * 16384;           \
        const char* lB_ = lds + ((4 * (TT) + 2 * (KH) + 1) & 7) * 16384;       \
        if ((CH) == 0) {                                                       \
            _Pragma("unroll")                                                  \
            for (int j_ = 0; j_ < 4; ++j_) bfr[j_] = *(const bf16x8*)(lB_ + boff[j_]); \
        }                                                                      \
        bf16x8 af_[4];                                                         \
        _Pragma("unroll")                                                      \
        for (int ii_ = 0; ii_ < 4; ++ii_) af_[ii_] = *(const bf16x8*)(lA_ + aoff[(CH) * 4 + ii_]); \
        asm volatile("s_waitcnt lgkmcnt(0)" ::: "memory");                     \
        __builtin_amdgcn_sched_barrier(0);                                     \
        __builtin_amdgcn_s_setprio(1);                                         \
        _Pragma("unroll")                                                      \
        for (int ii_ = 0; ii_ < 4; ++ii_)                                      \
            _Pragma("unroll")                                                  \
            for (int j_ = 0; j_ < 4; ++j_)                                     \
                acc[(CH) * 4 + ii_][j_] = __builtin_amdgcn_mfma_f32_16x16x32_bf16(af_[ii_], bfr[j_], acc[(CH) * 4 + ii_][j_], 0, 0, 0); \
        __builtin_amdgcn_s_setprio(0);                                         \
    } while (0)

    // prologue: 4 half-tiles in flight
    STAGE_HT(0); STAGE_HT(1); STAGE_HT(2); STAGE_HT(3);

    bf16x8 bfr[4];
#pragma unroll 1
    for (int T = 0; T < 11; ++T) {
#pragma unroll
        for (int pp = 0; pp < 4; ++pp) {
            STAGE_HT(4 * T + pp + 4);
            asm volatile("s_waitcnt vmcnt(6)" ::: "memory");
            __builtin_amdgcn_s_barrier();
            COMPUTE(T, pp >> 1, pp & 1);
        }
    }
    // T = 11 tail (phases 44-47): drain 4 -> 2 -> 0
    asm volatile("s_waitcnt vmcnt(4)" ::: "memory");
    __builtin_amdgcn_s_barrier();
    COMPUTE(11, 0, 0);
    asm volatile("s_waitcnt vmcnt(2)" ::: "memory");
    __builtin_amdgcn_s_barrier();
    COMPUTE(11, 0, 1);
    asm volatile("s_waitcnt vmcnt(0)" ::: "memory");
    __builtin_amdgcn_s_barrier();
    COMPUTE(11, 1, 0);
    __builtin_amdgcn_s_barrier();
    COMPUTE(11, 1, 1);
#undef STAGE_HT
#undef COMPUTE

    // epilogue: per-row top2 over this wave's 64 cols, in two 64-row halves.
    // C layout: col = ll, row = lh*4 + reg (within each 16x16 tile)
    const int colg0 = nb * 256 + wc * 64 + ll;
    const int cc = nb * 4 + wc;
#pragma unroll
    for (int ih = 0; ih < 2; ++ih) {
        float b1[16], b2[16];
        int k1[16];
#pragma unroll
        for (int q = 0; q < 16; ++q) { b1[q] = 3.4e38f; b2[q] = 3.4e38f; k1[q] = 0; }
#pragma unroll
        for (int j = 0; j < 4; ++j) {
            const int kcol = colg0 + j * 16;
            const float eq = esq[kcol];
#pragma unroll
            for (int ii = 0; ii < 4; ++ii)
#pragma unroll
                for (int r = 0; r < 4; ++r) {
                    const float s = fmaf(-2.f, acc[ih * 4 + ii][j][r], eq);
                    const int q = ii * 4 + r;
                    if (s < b1[q]) { b2[q] = b1[q]; b1[q] = s; k1[q] = kcol; }
                    else if (s < b2[q]) { b2[q] = s; }
                }
        }
        // merge the 16 col-lanes (masks 1,2,4,8 stay within the 16-lane group)
#pragma unroll
        for (int msk = 1; msk <= 8; msk <<= 1) {
#pragma unroll
            for (int q = 0; q < 16; ++q) {
                const float ob1 = __shfl_xor(b1[q], msk, 64);
                const int   ok1 = __shfl_xor(k1[q], msk, 64);
                const float ob2 = __shfl_xor(b2[q], msk, 64);
                if (ob1 < b1[q] || (ob1 == b1[q] && ok1 < k1[q])) {
                    b2[q] = fminf(b1[q], ob2); b1[q] = ob1; k1[q] = ok1;
                } else {
                    b2[q] = fminf(b2[q], ob1);
                }
            }
        }
        if (ll == 0) {
#pragma unroll
            for (int q = 0; q < 16; ++q) {
                const int ii = q >> 2, r = q & 3;
                const int row = mb * 256 + wr * 128 + ih * 64 + ii * 16 + lh * 4 + r;
                top2[(size_t)cc * NROWS + row] = make_float4(b1[q], __int_as_float(k1[q]), b2[q], 0.f);
            }
        }
    }
}

// ---------------- reduce: merge 64 col-chunks per row; compact ambiguous rows ----------------
__global__ __launch_bounds__(256) void reduce_top2_kernel(const float4* __restrict__ top2,
                                                          int* __restrict__ bidx,
                                                          int* __restrict__ flags,
                                                          int* __restrict__ list,
                                                          unsigned long long* __restrict__ res,
                                                          int* __restrict__ cnt) {
    const int row = blockIdx.x * 256 + threadIdx.x;
    float b1 = 3.4e38f, b2 = 3.4e38f;
    int k1 = 0x7fffffff;
#pragma unroll 8
    for (int c = 0; c < 64; ++c) {
        const float4 v = top2[(size_t)c * NROWS + row];
        const float ob1 = v.x, ob2 = v.z;
        const int ok1 = __float_as_int(v.y);
        if (ob1 < b1 || (ob1 == b1 && ok1 < k1)) { b2 = fminf(b1, ob2); b1 = ob1; k1 = ok1; }
        else { b2 = fminf(b2, ob1); }
    }
    bidx[row] = k1;
    const int f = (b2 - b1 <= DELTA) ? 1 : 0;
    flags[row] = f;
    if (f) {
        res[row] = ~0ULL;
        const int slot = atomicAdd(cnt, 1);
        list[slot] = row;
    }
}

// ---------------- rescore8: exact fp32 rescore, 8 rows x 256-code chunk per block ----------------
__global__ __launch_bounds__(256) void rescore8_kernel(const float* __restrict__ x,
                                                       const float* __restrict__ emb,
                                                       const float* __restrict__ esq,
                                                       const int* __restrict__ list,
                                                       const int* __restrict__ cnt,
                                                       unsigned long long* __restrict__ res) {
    __shared__ float xs[8][CCH];
    __shared__ int rid[8];
    const int t = threadIdx.x;
    const int q = blockIdx.x & 15;            // code chunk
    const int eg = blockIdx.x >> 4;           // entry group
    const int count = *cnt;
    const int k = q * 256 + t;
    const float eq = esq[k];
    const float* ek = emb + (size_t)k * CCH;

    for (int e8 = eg * 8; e8 < count; e8 += 128 * 8) {
        if (t < 8) rid[t] = (e8 + t < count) ? list[e8 + t] : -1;
        __syncthreads();
#pragma unroll
        for (int r = 0; r < 8; ++r) {
            const int rr = rid[r];
            if (rr >= 0) {
                const int b = rr >> 10, p = rr & 1023;
                xs[r][t] = x[((size_t)b * CCH + t) * N_PIX + p];
            }
        }
        __syncthreads();

        float dot[8];
#pragma unroll
        for (int r = 0; r < 8; ++r) dot[r] = 0.f;
#pragma unroll 8
        for (int c4 = 0; c4 < 64; ++c4) {
            const float4 e4 = *(const float4*)(ek + c4 * 4);
#pragma unroll
            for (int r = 0; r < 8; ++r) {
                const float4 xv = *(const float4*)(&xs[r][c4 * 4]);
                dot[r] = fmaf(xv.x, e4.x, dot[r]);
                dot[r] = fmaf(xv.y, e4.y, dot[r]);
                dot[r] = fmaf(xv.z, e4.z, dot[r]);
                dot[r] = fmaf(xv.w, e4.w, dot[r]);
            }
        }
#pragma unroll
        for (int r = 0; r < 8; ++r) {
            const float s = fmaf(-2.f, dot[r], eq);
            unsigned long long key = (((unsigned long long)mono(s)) << 32) | (unsigned)k;
#pragma unroll
            for (int off = 32; off > 0; off >>= 1) {
                const unsigned long long ok = __shfl_xor(key, off, 64);
                if (ok < key) key = ok;
            }
            if ((t & 63) == 0 && rid[r] >= 0)
                atomicMin(&res[rid[r]], key);
        }
        __syncthreads();
    }
}

// ---------------- apply: copy resolved indices for flagged rows ----------------
__global__ __launch_bounds__(256) void apply_kernel(const int* __restrict__ flags,
                                                    const unsigned long long* __restrict__ res,
                                                    int* __restrict__ bidx) {
    const int row = blockIdx.x * 256 + threadIdx.x;
    if (flags[row]) bidx[row] = (int)(res[row] & 0xFFFFFFFFULL);
}

// ---------------- fallback fp32 argmin (known-good) if ws too small ----------------
#define BROWS 32
#define FKTILE 256
#define FDCH 16
__global__ __launch_bounds__(256, 2) void argmin_fb_kernel(
    const float* __restrict__ x, const float* __restrict__ emb,
    const float* __restrict__ esq, int* __restrict__ bidx)
{
    __shared__ float xs[CCH * BROWS];
    __shared__ float es[FDCH * FKTILE];
    const int t = threadIdx.x;
    const int w = t >> 6;
    const int l = t & 63;
    const int n0 = blockIdx.x * BROWS;
    const int b = n0 >> 10;
    const int pixbase = n0 & (N_PIX - 1);
    const float* xb = x + (size_t)b * CCH * N_PIX + pixbase;
    {
        const int p4 = (t & 7) * 4;
        const int crow = t >> 3;
#pragma unroll
        for (int i = 0; i < 8; ++i) {
            const int c = i * 32 + crow;
            *(float4*)(xs + c * BROWS + p4) = *(const float4*)(xb + (size_t)c * N_PIX + p4);
        }
    }
    float best[8]; int bk[8];
#pragma unroll
    for (int r = 0; r < 8; ++r) { best[r] = 3.4e38f; bk[r] = 0; }
    float acc[8][4];
#pragma unroll
    for (int r = 0; r < 8; ++r)
#pragma unroll
        for (int j = 0; j < 4; ++j) acc[r][j] = 0.f;
    for (int kt = 0; kt < KCODES / FKTILE; ++kt) {
        for (int dc = 0; dc < CCH / FDCH; ++dc) {
            __syncthreads();
            {
                const float* src = emb + (size_t)(kt * FKTILE + t) * CCH + dc * FDCH;
#pragma unroll
                for (int c = 0; c < FDCH; ++c) es[c * FKTILE + t] = src[c];
            }
            __syncthreads();
            const int c0 = dc * FDCH;
            const float* ep = es + 4 * l;
            const float* xp = xs + c0 * BROWS + w * 8;
#pragma unroll
            for (int c = 0; c < FDCH; ++c) {
                const float4 ev = *(const float4*)(ep + c * FKTILE);
                const float4 xa = *(const float4*)(xp + c * BROWS);
                const float4 xc = *(const float4*)(xp + c * BROWS + 4);
                const float xr8[8] = {xa.x, xa.y, xa.z, xa.w, xc.x, xc.y, xc.z, xc.w};
#pragma unroll
                for (int r = 0; r < 8; ++r) {
                    acc[r][0] = fmaf(xr8[r], ev.x, acc[r][0]);
                    acc[r][1] = fmaf(xr8[r], ev.y, acc[r][1]);
                    acc[r][2] = fmaf(xr8[r], ev.z, acc[r][2]);
                    acc[r][3] = fmaf(xr8[r], ev.w, acc[r][3]);
                }
            }
        }
        const float4 q = *(const float4*)(esq + kt * FKTILE + 4 * l);
        const float qr[4] = {q.x, q.y, q.z, q.w};
#pragma unroll
        for (int r = 0; r < 8; ++r)
#pragma unroll
            for (int j = 0; j < 4; ++j) {
                const float s = fmaf(-2.f, acc[r][j], qr[j]);
                if (s < best[r]) { best[r] = s; bk[r] = kt * FKTILE + 4 * l + j; }
                acc[r][j] = 0.f;
            }
    }
#pragma unroll
    for (int r = 0; r < 8; ++r) {
        float bv = best[r]; int bi = bk[r];
#pragma unroll
        for (int off = 32; off > 0; off >>= 1) {
            const float ov = __shfl_xor(bv, off, 64);
            const int   oi = __shfl_xor(bi, off, 64);
            if (ov < bv || (ov == bv && oi < bi)) { bv = ov; bi = oi; }
        }
        if (l == 0) bidx[n0 + w * 8 + r] = bi;
    }
}

// ---------------- gather + oup + loss partials ----------------
__global__ __launch_bounds__(256) void gather_kernel(
    const float* __restrict__ x, const float* __restrict__ emb,
    const int* __restrict__ bidx, float* __restrict__ oup,
    float* __restrict__ partial)
{
    __shared__ int sidx[64];
    __shared__ float red[256];
    const int t = threadIdx.x;
    const int n0 = blockIdx.x * 64;
    const int b = n0 >> 10;
    const int pixbase = n0 & (N_PIX - 1);
    if (t < 64) sidx[t] = bidx[n0 + t];
    __syncthreads();
    const int pl = t & 63;
    const int w = t >> 6;
    const int k = sidx[pl];
    const float* xbp = x + (size_t)b * CCH * N_PIX + pixbase + pl;
    float* ob = oup + (size_t)b * CCH * N_PIX + pixbase + pl;
    const float* ek = emb + (size_t)k * CCH + w * 64;
    float lsum = 0.f;
#pragma unroll 4
    for (int cc = 0; cc < 16; ++cc) {
        const float4 e4 = *(const float4*)(ek + cc * 4);
        const float er[4] = {e4.x, e4.y, e4.z, e4.w};
#pragma unroll
        for (int j = 0; j < 4; ++j) {
            const size_t off = (size_t)(w * 64 + cc * 4 + j) * N_PIX;
            const float xv = xbp[off];
            ob[off] = er[j];
            const float d = xv - er[j];
            lsum = fmaf(d, d, lsum);
        }
    }
    red[t] = lsum;
    __syncthreads();
#pragma unroll
    for (int s = 128; s > 0; s >>= 1) {
        if (t < s) red[t] += red[t + s];
        __syncthreads();
    }
    if (t == 0) partial[blockIdx.x] = red[0];
}

__global__ __launch_bounds__(256) void finalize_kernel(const float* __restrict__ partial,
                                                       float* __restrict__ out_losses) {
    __shared__ float red[256];
    const int t = threadIdx.x;
    red[t] = partial[t] + partial[t + 256];
    __syncthreads();
    for (int s = 128; s > 0; s >>= 1) {
        if (t < s) red[t] += red[t + s];
        __syncthreads();
    }
    if (t == 0) {
        const float loss = red[0] * (1.0f / 8388608.0f);
        out_losses[0] = loss;
        out_losses[1] = loss;
    }
}

extern "C" void kernel_launch(void* const* d_in, const int* in_sizes, int n_in,
                              void* d_out, int out_size, void* d_ws, size_t ws_size,
                              hipStream_t stream) {
    const float* x = (const float*)d_in[0];
    const float* emb = (const float*)d_in[1];
    float* out = (float*)d_out;

    char* ws = (char*)d_ws;
    float* esq = (float*)(ws + OFF_ESQ);
    int* bidx = (int*)(ws + OFF_BIDX);
    int* flags = (int*)(ws + OFF_FLAGS);
    float* partial = (float*)(ws + OFF_PART);

    esq_kernel<<<KCODES / 4, 256, 0, stream>>>(emb, esq);

    if (ws_size >= (size_t)WS_NEEDED) {
        float4* top2 = (float4*)(ws + OFF_TOP2);
        char* A = ws + OFF_A;
        char* B = ws + OFF_B;
        int* list = (int*)(ws + OFF_LIST);
        unsigned long long* res = (unsigned long long*)(ws + OFF_RES);
        int* cnt = (int*)(ws + OFF_CNT);
        conv_x_kernel<<<NROWS / 64, 256, 0, stream>>>(x, A);
        conv_e_kernel<<<KCODES / 64, 256, 0, stream>>>(emb, B, cnt);
        mfma_top2_kernel<<<dim3(KCODES / 256, NROWS / 256), 512, 0, stream>>>(A, B, esq, top2);
        reduce_top2_kernel<<<NROWS / 256, 256, 0, stream>>>(top2, bidx, flags, list, res, cnt);
        rescore8_kernel<<<2048, 256, 0, stream>>>(x, emb, esq, list, cnt, res);
        apply_kernel<<<NROWS / 256, 256, 0, stream>>>(flags, res, bidx);
    } else {
        argmin_fb_kernel<<<NROWS / BROWS, 256, 0, stream>>>(x, emb, esq, bidx);
    }

    gather_kernel<<<NROWS / 64, 256, 0, stream>>>(x, emb, bidx, out, partial);
    finalize_kernel<<<1, 256, 0, stream>>>(partial, out + 8388608);
}

// Round 19
// 318.378 us; speedup vs baseline: 2.0934x; 1.3033x over previous
//
#include <hip/hip_runtime.h>

#define N_PIX 1024      // 32*32 pixels per image
#define BATCH 32
#define CCH 256         // channels == code dim
#define KCODES 4096
#define NROWS 32768     // BATCH * N_PIX
#define DELTA 0.0625f   // rescore margin (approx-score error bound ~0.003 typ, 0.05 worst)

typedef __attribute__((ext_vector_type(8))) short bf16x8;
typedef __attribute__((ext_vector_type(4))) float f32x4;

// ---- ws layout (bytes) ----
#define OFF_ESQ   0u
#define OFF_BIDX  16384u
#define OFF_FLAGS 147456u
#define OFF_PART  278528u
#define OFF_TOP2  524288u                    // 64 chunks x 32768 rows x float4 = 32 MB
#define OFF_A     34078720u                  // 256 mtiles x 16 sub x 8 KB = 32 MB (fragment-direct)
#define OFF_B     67633152u                  // 32 ntiles x 16 sub x 8 KB = 4 MB (interleaved, swizzled)
#define WS_NEEDED 71827456u
// list/res/cnt live INSIDE the A region (dead after mfma_top2; rewritten every call by conv_x first)
#define OFF_LIST  OFF_A                      // 32768 i32 = 128 KB
#define OFF_RES   (OFF_A + 131072u)          // 32768 u64 = 256 KB
#define OFF_CNT   (OFF_A + 131072u + 262144u)

// B swizzle for 64-B rows (ds_read side): spreads 16-lane b128 quarters over all
// 8 bank-groups per 8 rows. Applied at conv (pre-swizzled global) + ds_read.
#define ROWSWZ(row) ((((row) >> 1) & 3) << 4)

// round-to-nearest-even fp32 -> bf16 bits
__device__ __forceinline__ unsigned short f2bf(float v) {
    unsigned u = __float_as_uint(v);
    return (unsigned short)((u + 0x7FFFu + ((u >> 16) & 1u)) >> 16);
}
__device__ __forceinline__ float bf2f(unsigned short h) {
    return __uint_as_float(((unsigned)h) << 16);
}
// monotone float -> uint (total order preserving)
__device__ __forceinline__ unsigned mono(float s) {
    unsigned u = __float_as_uint(s);
    return (u & 0x80000000u) ? ~u : (u | 0x80000000u);
}

__device__ __forceinline__ void gload_lds16(const void* g, void* l) {
    __builtin_amdgcn_global_load_lds(
        (const __attribute__((address_space(1))) unsigned int*)g,
        (__attribute__((address_space(3))) unsigned int*)l, 16, 0, 0);
}

// ---------------- esq (fallback path only): e_sq[k] = sum_c emb[k][c]^2 ----------------
__global__ __launch_bounds__(256) void esq_kernel(const float* __restrict__ emb,
                                                  float* __restrict__ esq) {
    const int t = threadIdx.x;
    const int w = t >> 6, l = t & 63;
    const int k = blockIdx.x * 4 + w;
    const float4 v = *(const float4*)(emb + (size_t)k * CCH + l * 4);
    float s = v.x * v.x + v.y * v.y + v.z * v.z + v.w * v.w;
#pragma unroll
    for (int off = 32; off > 0; off >>= 1) s += __shfl_down(s, off);
    if (l == 0) esq[k] = s;
}

// ---------------- conv_x: x fp32 NCHW -> fragment-direct bf16 hi/lo A-subtiles ----------------
// A2[mtile][sub 16][wg 2][i 4][lane 64][16 B]; 128 KB per mtile.
__global__ __launch_bounds__(256) void conv_x_kernel(const float* __restrict__ x,
                                                     char* __restrict__ A) {
    const int t = threadIdx.x;
    const int m = blockIdx.x * 64 + (t & 63);
    const int kt = t >> 6;                       // 0..3
    const int b = m >> 10, p = m & 1023;
    const float* src = x + ((size_t)b * CCH + kt * 64) * N_PIX + p;
    char* tbase = A + (size_t)(m >> 7) * 131072;   // 128 KB per mtile
    const int wg = (m >> 6) & 1, fi = (m >> 4) & 3, ll = m & 15;
    const int fragbase = wg * 4096 + fi * 1024;    // + lane*16 within sub
#pragma unroll
    for (int g = 0; g < 8; ++g) {
        unsigned hv[4], lv[4];
#pragma unroll
        for (int e2 = 0; e2 < 4; ++e2) {
            const float v0 = src[(size_t)(g * 8 + e2 * 2 + 0) * N_PIX];
            const float v1 = src[(size_t)(g * 8 + e2 * 2 + 1) * N_PIX];
            const unsigned short h0 = f2bf(v0), h1 = f2bf(v1);
            const unsigned short l0 = f2bf(v0 - bf2f(h0)), l1 = f2bf(v1 - bf2f(h1));
            hv[e2] = (unsigned)h0 | ((unsigned)h1 << 16);
            lv[e2] = (unsigned)l0 | ((unsigned)l1 << 16);
        }
        const int sub_hi = kt * 2 + (g >> 2);            // 0..7
        const int lane = (g & 3) * 16 + ll;
        const int byte = fragbase + lane * 16;
        *(uint4*)(tbase + sub_hi * 8192 + byte)       = make_uint4(hv[0], hv[1], hv[2], hv[3]);
        *(uint4*)(tbase + (8 + sub_hi) * 8192 + byte) = make_uint4(lv[0], lv[1], lv[2], lv[3]);
    }
}

// ---------------- conv_e: embedding -> pre-swizzled bf16 hi/lo B-subtiles (+esq fused, +zero cnt) ----------------
__global__ __launch_bounds__(256) void conv_e_kernel(const float* __restrict__ emb,
                                                     char* __restrict__ B,
                                                     float* __restrict__ esq,
                                                     int* __restrict__ cnt) {
    __shared__ float ps[4][64];
    const int t = threadIdx.x;
    if (blockIdx.x == 0 && t == 0) *cnt = 0;   // runs after conv_x (which clobbers this region)
    const int n = blockIdx.x * 64 + (t & 63);
    const int kt = t >> 6;
    const float* src = emb + (size_t)n * CCH + kt * 64;
    const int row = n & 127;
    char* tbase = B + (size_t)(n >> 7) * 131072;   // 128 KB per ntile
    const int swz = ROWSWZ(row);
    float sq = 0.f;
#pragma unroll
    for (int g = 0; g < 8; ++g) {
        const float4 a = *(const float4*)(src + g * 8);
        const float4 c = *(const float4*)(src + g * 8 + 4);
        const float vr[8] = {a.x, a.y, a.z, a.w, c.x, c.y, c.z, c.w};
#pragma unroll
        for (int e = 0; e < 8; ++e) sq = fmaf(vr[e], vr[e], sq);
        unsigned hv[4], lv[4];
#pragma unroll
        for (int e2 = 0; e2 < 4; ++e2) {
            const unsigned short h0 = f2bf(vr[e2 * 2]), h1 = f2bf(vr[e2 * 2 + 1]);
            const unsigned short l0 = f2bf(vr[e2 * 2] - bf2f(h0));
            const unsigned short l1 = f2bf(vr[e2 * 2 + 1] - bf2f(h1));
            hv[e2] = (unsigned)h0 | ((unsigned)h1 << 16);
            lv[e2] = (unsigned)l0 | ((unsigned)l1 << 16);
        }
        const int sub_hi = kt * 2 + (g >> 2);
        const int byte = (row * 64 + (g & 3) * 16) ^ swz;
        *(uint4*)(tbase + sub_hi * 8192 + byte)       = make_uint4(hv[0], hv[1], hv[2], hv[3]);
        *(uint4*)(tbase + (8 + sub_hi) * 8192 + byte) = make_uint4(lv[0], lv[1], lv[2], lv[3]);
    }
    ps[kt][t & 63] = sq;
    __syncthreads();
    if (kt == 0)
        esq[n] = ps[0][t & 63] + ps[1][t & 63] + ps[2][t & 63] + ps[3][t & 63];
}

// ---------------- mfma_top2: 128x128 tile GEMM, 8 steps x 48 MFMA (R15, proven 253.6 us) ----------------
// Counted vmcnt(12) pipeline + TRIPLE-buffered B LDS -> one barrier/step. A frags
// global->register (fragment-direct layout). (256,3): unified reg budget ~148/thr.
__global__ __launch_bounds__(256, 3) void mfma_top2_kernel(
    const char* __restrict__ Ag, const char* __restrict__ Bg,
    const float* __restrict__ esq, float4* __restrict__ top2)
{
    __shared__ char lds[3 * 16384];   // per buf: Bhi 8K | Blo 8K
    const int t = threadIdx.x;
    const int w = t >> 6, l = t & 63;
    const int nb = blockIdx.x;    // code-block (fast axis)
    const int mb = blockIdx.y;    // row-block
    const int lh = l >> 4, ll = l & 15;

    int boff[4];
#pragma unroll
    for (int i = 0; i < 4; ++i) {
        const int br = (w & 1) * 64 + i * 16 + ll;
        boff[i] = (br * 64 + lh * 16) ^ ROWSWZ(br);
    }

    const char* Abase = Ag + (size_t)mb * 131072 + (w >> 1) * 4096 + l * 16;
    const char* Bbase = Bg + (size_t)nb * 131072;

    f32x4 acc[4][4];
#pragma unroll
    for (int i = 0; i < 4; ++i)
#pragma unroll
        for (int j = 0; j < 4; ++j) acc[i][j] = 0.f;

    bf16x8 afh[2][4], afl[2][4];   // double-buffered A hi/lo fragments (wave-private)

#define LOADA(SS, PAR) do {                                                    \
        const char* Ah_ = Abase + (SS) * 8192;                                 \
        const char* Al_ = Abase + (8 + (SS)) * 8192;                           \
        _Pragma("unroll")                                                      \
        for (int i_ = 0; i_ < 4; ++i_) {                                       \
            afh[(PAR)][i_] = *(const bf16x8*)(Ah_ + i_ * 1024);                \
            afl[(PAR)][i_] = *(const bf16x8*)(Al_ + i_ * 1024);                \
        }                                                                      \
    } while (0)

#define STAGEB(SS, BUF) do {                                                   \
        const char* Bh_ = Bbase + (SS) * 8192;                                 \
        const char* Bl_ = Bbase + (8 + (SS)) * 8192;                           \
        char* dst_ = lds + (BUF) * 16384;                                      \
        gload_lds16(Bh_ + t * 16,        dst_ + t * 16);                       \
        gload_lds16(Bh_ + 4096 + t * 16, dst_ + 4096 + t * 16);                \
        gload_lds16(Bl_ + t * 16,        dst_ + 8192 + t * 16);                \
        gload_lds16(Bl_ + 4096 + t * 16, dst_ + 12288 + t * 16);               \
    } while (0)

    LOADA(0, 0);
    STAGEB(0, 0);

#pragma unroll
    for (int s = 0; s < 8; ++s) {
        const int cur = s % 3;         // compile-time under full unroll
        const int ap = s & 1;
        if (s < 7) {                   // issue next step's 12 vmem ops
            LOADA(s + 1, ap ^ 1);
            STAGEB(s + 1, (s + 1) % 3);
            asm volatile("s_waitcnt vmcnt(12)" ::: "memory");   // batch-s landed
        } else {
            asm volatile("s_waitcnt vmcnt(0)" ::: "memory");
        }
        __builtin_amdgcn_s_barrier();  // single barrier/step (3-buf makes it safe)
        __builtin_amdgcn_sched_barrier(0);

        const char* lb = lds + cur * 16384;
        bf16x8 bh[4];
#pragma unroll
        for (int i = 0; i < 4; ++i) bh[i] = *(const bf16x8*)(lb + boff[i]);
        __builtin_amdgcn_s_setprio(1);
#pragma unroll
        for (int i = 0; i < 4; ++i)
#pragma unroll
            for (int j = 0; j < 4; ++j)
                acc[i][j] = __builtin_amdgcn_mfma_f32_16x16x32_bf16(afh[ap][i], bh[j], acc[i][j], 0, 0, 0);
#pragma unroll
        for (int i = 0; i < 4; ++i)
#pragma unroll
            for (int j = 0; j < 4; ++j)
                acc[i][j] = __builtin_amdgcn_mfma_f32_16x16x32_bf16(afl[ap][i], bh[j], acc[i][j], 0, 0, 0);
        bf16x8 bl[4];
#pragma unroll
        for (int i = 0; i < 4; ++i) bl[i] = *(const bf16x8*)(lb + 8192 + boff[i]);
#pragma unroll
        for (int i = 0; i < 4; ++i)
#pragma unroll
            for (int j = 0; j < 4; ++j)
                acc[i][j] = __builtin_amdgcn_mfma_f32_16x16x32_bf16(afh[ap][i], bl[j], acc[i][j], 0, 0, 0);
        __builtin_amdgcn_s_setprio(0);
    }
#undef LOADA
#undef STAGEB

    // epilogue: per-row top2 over this wave's 64 cols.
    // C layout: col = ll, row = lh*4 + reg  (within each 16x16 tile)
    float b1[16], b2[16];
    int k1[16];
#pragma unroll
    for (int q = 0; q < 16; ++q) { b1[q] = 3.4e38f; b2[q] = 3.4e38f; k1[q] = 0; }
    const int colg0 = nb * 128 + (w & 1) * 64 + ll;
#pragma unroll
    for (int j = 0; j < 4; ++j) {
        const int kcol = colg0 + j * 16;
        const float eq = esq[kcol];
#pragma unroll
        for (int i = 0; i < 4; ++i)
#pragma unroll
            for (int r = 0; r < 4; ++r) {
                const float s = fmaf(-2.f, acc[i][j][r], eq);
                const int q = i * 4 + r;
                if (s < b1[q]) { b2[q] = b1[q]; b1[q] = s; k1[q] = kcol; }
                else if (s < b2[q]) { b2[q] = s; }
            }
    }
    // merge the 16 col-lanes (masks 1,2,4,8 stay within the 16-lane group)
#pragma unroll
    for (int msk = 1; msk <= 8; msk <<= 1) {
#pragma unroll
        for (int q = 0; q < 16; ++q) {
            const float ob1 = __shfl_xor(b1[q], msk, 64);
            const int   ok1 = __shfl_xor(k1[q], msk, 64);
            const float ob2 = __shfl_xor(b2[q], msk, 64);
            if (ob1 < b1[q] || (ob1 == b1[q] && ok1 < k1[q])) {
                b2[q] = fminf(b1[q], ob2); b1[q] = ob1; k1[q] = ok1;
            } else {
                b2[q] = fminf(b2[q], ob1);
            }
        }
    }
    if (ll == 0) {
        const size_t cc = (size_t)(nb * 2 + (w & 1)) * NROWS;
#pragma unroll
        for (int q = 0; q < 16; ++q) {
            const int i = q >> 2, r = q & 3;
            const int row = mb * 128 + (w >> 1) * 64 + i * 16 + lh * 4 + r;
            top2[cc + row] = make_float4(b1[q], __int_as_float(k1[q]), b2[q], 0.f);
        }
    }
}

// ---------------- reduce: merge 64 col-chunks per row; compact ambiguous rows ----------------
__global__ __launch_bounds__(256) void reduce_top2_kernel(const float4* __restrict__ top2,
                                                          int* __restrict__ bidx,
                                                          int* __restrict__ flags,
                                                          int* __restrict__ list,
                                                          unsigned long long* __restrict__ res,
                                                          int* __restrict__ cnt) {
    const int row = blockIdx.x * 256 + threadIdx.x;
    float b1 = 3.4e38f, b2 = 3.4e38f;
    int k1 = 0x7fffffff;
#pragma unroll 8
    for (int c = 0; c < 64; ++c) {
        const float4 v = top2[(size_t)c * NROWS + row];
        const float ob1 = v.x, ob2 = v.z;
        const int ok1 = __float_as_int(v.y);
        if (ob1 < b1 || (ob1 == b1 && ok1 < k1)) { b2 = fminf(b1, ob2); b1 = ob1; k1 = ok1; }
        else { b2 = fminf(b2, ob1); }
    }
    bidx[row] = k1;
    const int f = (b2 - b1 <= DELTA) ? 1 : 0;
    flags[row] = f;
    if (f) {
        res[row] = ~0ULL;
        const int slot = atomicAdd(cnt, 1);
        list[slot] = row;
    }
}

// ---------------- rescore8: exact fp32 rescore, 8 rows x 256-code chunk per block ----------------
__global__ __launch_bounds__(256) void rescore8_kernel(const float* __restrict__ x,
                                                       const float* __restrict__ emb,
                                                       const float* __restrict__ esq,
                                                       const int* __restrict__ list,
                                                       const int* __restrict__ cnt,
                                                       unsigned long long* __restrict__ res) {
    __shared__ float xs[8][CCH];
    __shared__ int rid[8];
    const int t = threadIdx.x;
    const int q = blockIdx.x & 15;            // code chunk
    const int eg = blockIdx.x >> 4;           // entry group
    const int count = *cnt;
    const int k = q * 256 + t;
    const float eq = esq[k];
    const float* ek = emb + (size_t)k * CCH;

    for (int e8 = eg * 8; e8 < count; e8 += 128 * 8) {
        if (t < 8) rid[t] = (e8 + t < count) ? list[e8 + t] : -1;
        __syncthreads();
#pragma unroll
        for (int r = 0; r < 8; ++r) {
            const int rr = rid[r];
            if (rr >= 0) {
                const int b = rr >> 10, p = rr & 1023;
                xs[r][t] = x[((size_t)b * CCH + t) * N_PIX + p];
            }
        }
        __syncthreads();

        float dot[8];
#pragma unroll
        for (int r = 0; r < 8; ++r) dot[r] = 0.f;
#pragma unroll 8
        for (int c4 = 0; c4 < 64; ++c4) {
            const float4 e4 = *(const float4*)(ek + c4 * 4);
#pragma unroll
            for (int r = 0; r < 8; ++r) {
                const float4 xv = *(const float4*)(&xs[r][c4 * 4]);
                dot[r] = fmaf(xv.x, e4.x, dot[r]);
                dot[r] = fmaf(xv.y, e4.y, dot[r]);
                dot[r] = fmaf(xv.z, e4.z, dot[r]);
                dot[r] = fmaf(xv.w, e4.w, dot[r]);
            }
        }
#pragma unroll
        for (int r = 0; r < 8; ++r) {
            const float s = fmaf(-2.f, dot[r], eq);
            unsigned long long key = (((unsigned long long)mono(s)) << 32) | (unsigned)k;
#pragma unroll
            for (int off = 32; off > 0; off >>= 1) {
                const unsigned long long ok = __shfl_xor(key, off, 64);
                if (ok < key) key = ok;
            }
            if ((t & 63) == 0 && rid[r] >= 0)
                atomicMin(&res[rid[r]], key);
        }
        __syncthreads();
    }
}

// ---------------- apply: copy resolved indices for flagged rows ----------------
__global__ __launch_bounds__(256) void apply_kernel(const int* __restrict__ flags,
                                                    const unsigned long long* __restrict__ res,
                                                    int* __restrict__ bidx) {
    const int row = blockIdx.x * 256 + threadIdx.x;
    if (flags[row]) bidx[row] = (int)(res[row] & 0xFFFFFFFFULL);
}

// ---------------- fallback fp32 argmin (known-good) if ws too small ----------------
#define BROWS 32
#define FKTILE 256
#define FDCH 16
__global__ __launch_bounds__(256, 2) void argmin_fb_kernel(
    const float* __restrict__ x, const float* __restrict__ emb,
    const float* __restrict__ esq, int* __restrict__ bidx)
{
    __shared__ float xs[CCH * BROWS];
    __shared__ float es[FDCH * FKTILE];
    const int t = threadIdx.x;
    const int w = t >> 6;
    const int l = t & 63;
    const int n0 = blockIdx.x * BROWS;
    const int b = n0 >> 10;
    const int pixbase = n0 & (N_PIX - 1);
    const float* xb = x + (size_t)b * CCH * N_PIX + pixbase;
    {
        const int p4 = (t & 7) * 4;
        const int crow = t >> 3;
#pragma unroll
        for (int i = 0; i < 8; ++i) {
            const int c = i * 32 + crow;
            *(float4*)(xs + c * BROWS + p4) = *(const float4*)(xb + (size_t)c * N_PIX + p4);
        }
    }
    float best[8]; int bk[8];
#pragma unroll
    for (int r = 0; r < 8; ++r) { best[r] = 3.4e38f; bk[r] = 0; }
    float acc[8][4];
#pragma unroll
    for (int r = 0; r < 8; ++r)
#pragma unroll
        for (int j = 0; j < 4; ++j) acc[r][j] = 0.f;
    for (int kt = 0; kt < KCODES / FKTILE; ++kt) {
        for (int dc = 0; dc < CCH / FDCH; ++dc) {
            __syncthreads();
            {
                const float* src = emb + (size_t)(kt * FKTILE + t) * CCH + dc * FDCH;
#pragma unroll
                for (int c = 0; c < FDCH; ++c) es[c * FKTILE + t] = src[c];
            }
            __syncthreads();
            const int c0 = dc * FDCH;
            const float* ep = es + 4 * l;
            const float* xp = xs + c0 * BROWS + w * 8;
#pragma unroll
            for (int c = 0; c < FDCH; ++c) {
                const float4 ev = *(const float4*)(ep + c * FKTILE);
                const float4 xa = *(const float4*)(xp + c * BROWS);
                const float4 xc = *(const float4*)(xp + c * BROWS + 4);
                const float xr8[8] = {xa.x, xa.y, xa.z, xa.w, xc.x, xc.y, xc.z, xc.w};
#pragma unroll
                for (int r = 0; r < 8; ++r) {
                    acc[r][0] = fmaf(xr8[r], ev.x, acc[r][0]);
                    acc[r][1] = fmaf(xr8[r], ev.y, acc[r][1]);
                    acc[r][2] = fmaf(xr8[r], ev.z, acc[r][2]);
                    acc[r][3] = fmaf(xr8[r], ev.w, acc[r][3]);
                }
            }
        }
        const float4 q = *(const float4*)(esq + kt * FKTILE + 4 * l);
        const float qr[4] = {q.x, q.y, q.z, q.w};
#pragma unroll
        for (int r = 0; r < 8; ++r)
#pragma unroll
            for (int j = 0; j < 4; ++j) {
                const float s = fmaf(-2.f, acc[r][j], qr[j]);
                if (s < best[r]) { best[r] = s; bk[r] = kt * FKTILE + 4 * l + j; }
                acc[r][j] = 0.f;
            }
    }
#pragma unroll
    for (int r = 0; r < 8; ++r) {
        float bv = best[r]; int bi = bk[r];
#pragma unroll
        for (int off = 32; off > 0; off >>= 1) {
            const float ov = __shfl_xor(bv, off, 64);
            const int   oi = __shfl_xor(bi, off, 64);
            if (ov < bv || (ov == bv && oi < bi)) { bv = ov; bi = oi; }
        }
        if (l == 0) bidx[n0 + w * 8 + r] = bi;
    }
}

// ---------------- gather + oup + loss partials ----------------
__global__ __launch_bounds__(256) void gather_kernel(
    const float* __restrict__ x, const float* __restrict__ emb,
    const int* __restrict__ bidx, float* __restrict__ oup,
    float* __restrict__ partial)
{
    __shared__ int sidx[64];
    __shared__ float red[256];
    const int t = threadIdx.x;
    const int n0 = blockIdx.x * 64;
    const int b = n0 >> 10;
    const int pixbase = n0 & (N_PIX - 1);
    if (t < 64) sidx[t] = bidx[n0 + t];
    __syncthreads();
    const int pl = t & 63;
    const int w = t >> 6;
    const int k = sidx[pl];
    const float* xbp = x + (size_t)b * CCH * N_PIX + pixbase + pl;
    float* ob = oup + (size_t)b * CCH * N_PIX + pixbase + pl;
    const float* ek = emb + (size_t)k * CCH + w * 64;
    float lsum = 0.f;
#pragma unroll 4
    for (int cc = 0; cc < 16; ++cc) {
        const float4 e4 = *(const float4*)(ek + cc * 4);
        const float er[4] = {e4.x, e4.y, e4.z, e4.w};
#pragma unroll
        for (int j = 0; j < 4; ++j) {
            const size_t off = (size_t)(w * 64 + cc * 4 + j) * N_PIX;
            const float xv = xbp[off];
            ob[off] = er[j];
            const float d = xv - er[j];
            lsum = fmaf(d, d, lsum);
        }
    }
    red[t] = lsum;
    __syncthreads();
#pragma unroll
    for (int s = 128; s > 0; s >>= 1) {
        if (t < s) red[t] += red[t + s];
        __syncthreads();
    }
    if (t == 0) partial[blockIdx.x] = red[0];
}

__global__ __launch_bounds__(256) void finalize_kernel(const float* __restrict__ partial,
                                                       float* __restrict__ out_losses) {
    __shared__ float red[256];
    const int t = threadIdx.x;
    red[t] = partial[t] + partial[t + 256];
    __syncthreads();
    for (int s = 128; s > 0; s >>= 1) {
        if (t < s) red[t] += red[t + s];
        __syncthreads();
    }
    if (t == 0) {
        const float loss = red[0] * (1.0f / 8388608.0f);
        out_losses[0] = loss;
        out_losses[1] = loss;
    }
}

extern "C" void kernel_launch(void* const* d_in, const int* in_sizes, int n_in,
                              void* d_out, int out_size, void* d_ws, size_t ws_size,
                              hipStream_t stream) {
    const float* x = (const float*)d_in[0];
    const float* emb = (const float*)d_in[1];
    float* out = (float*)d_out;

    char* ws = (char*)d_ws;
    float* esq = (float*)(ws + OFF_ESQ);
    int* bidx = (int*)(ws + OFF_BIDX);
    int* flags = (int*)(ws + OFF_FLAGS);
    float* partial = (float*)(ws + OFF_PART);

    if (ws_size >= (size_t)WS_NEEDED) {
        float4* top2 = (float4*)(ws + OFF_TOP2);
        char* A = ws + OFF_A;
        char* B = ws + OFF_B;
        int* list = (int*)(ws + OFF_LIST);
        unsigned long long* res = (unsigned long long*)(ws + OFF_RES);
        int* cnt = (int*)(ws + OFF_CNT);
        conv_x_kernel<<<NROWS / 64, 256, 0, stream>>>(x, A);
        conv_e_kernel<<<KCODES / 64, 256, 0, stream>>>(emb, B, esq, cnt);
        mfma_top2_kernel<<<dim3(KCODES / 128, NROWS / 128), 256, 0, stream>>>(A, B, esq, top2);
        reduce_top2_kernel<<<NROWS / 256, 256, 0, stream>>>(top2, bidx, flags, list, res, cnt);
        rescore8_kernel<<<2048, 256, 0, stream>>>(x, emb, esq, list, cnt, res);
        apply_kernel<<<NROWS / 256, 256, 0, stream>>>(flags, res, bidx);
    } else {
        esq_kernel<<<KCODES / 4, 256, 0, stream>>>(emb, esq);
        argmin_fb_kernel<<<NROWS / BROWS, 256, 0, stream>>>(x, emb, esq, bidx);
    }

    gather_kernel<<<NROWS / 64, 256, 0, stream>>>(x, emb, bidx, out, partial);
    finalize_kernel<<<1, 256, 0, stream>>>(partial, out + 8388608);
}